// Round 1
// 456.286 us; speedup vs baseline: 1.0910x; 1.0910x over previous
//
#include <hip/hip_runtime.h>

typedef unsigned short u16;
typedef __bf16 bf16x8 __attribute__((ext_vector_type(8)));
typedef short s16x4 __attribute__((ext_vector_type(4)));
typedef float f32x4 __attribute__((ext_vector_type(4)));

#define S_LEN 2048
#define NHEAD 16
#define QHEAD 192
#define EPS 1e-6f
#define ATTN_SCALE 0.07216878364870323f   /* 192^-0.5 */
#define QSCALE_LOG2E 0.10412011228586118f /* ATTN_SCALE * log2(e) */

__device__ __forceinline__ u16 f2bf(float f) {
    unsigned u = __builtin_bit_cast(unsigned, f);
    u = (u + 0x7FFFu + ((u >> 16) & 1u)) >> 16;
    return (u16)u;
}
__device__ __forceinline__ float bf2f(u16 h) {
    unsigned u = ((unsigned)h) << 16;
    return __builtin_bit_cast(float, u);
}

__device__ __forceinline__ void gl_lds16(const u16* g, u16* l) {
    __builtin_amdgcn_global_load_lds(
        (const __attribute__((address_space(1))) unsigned int*)g,
        (__attribute__((address_space(3))) unsigned int*)l,
        16, 0, 0);
}

#if defined(__has_builtin) && __has_builtin(__builtin_amdgcn_mfma_f32_16x16x16bf16_1k)
__device__ __forceinline__ f32x4 mfma16(s16x4 a, s16x4 b, f32x4 c) {
    return __builtin_amdgcn_mfma_f32_16x16x16bf16_1k(a, b, c, 0, 0, 0);
}
#else
__device__ __forceinline__ f32x4 mfma16(s16x4 a, s16x4 b, f32x4 c) {
    asm volatile("v_mfma_f32_16x16x16_bf16 %0, %1, %2, %0"
                 : "+v"(c) : "v"(a), "v"(b));
    return c;
}
#endif

// ---------------------------------------------------------------------------
// bf16 GEMM:  C[M][N] = A[M][K] @ Bt[N][K]^T   (unchanged)
// ---------------------------------------------------------------------------
template <int CF32>
__global__ __launch_bounds__(256, 2)
void gemm_bt(const u16* __restrict__ A, const u16* __restrict__ B,
             void* __restrict__ Cv, int K, int lda, int ldb, int ldc)
{
    const int tid = threadIdx.x;
    const int wave = tid >> 6, lane = tid & 63;
    const int q = lane >> 4, r = lane & 15;
    const int tm = blockIdx.y, tn = blockIdx.x;

    __shared__ __align__(16) u16 Al[128 * 32];
    __shared__ __align__(16) u16 Bl[128 * 32];

    const int lr = lane & 15;
    const int lc = (lane >> 4) * 8;
    const u16* ag0 = A + (long)(tm * 128 + wave * 32 + lr) * lda + lc;
    const u16* ag1 = ag0 + 16 * (long)lda;
    const u16* bg0 = B + (long)(tn * 128 + wave * 32 + lr) * ldb + lc;
    const u16* bg1 = bg0 + 16 * (long)ldb;
    u16* al0 = &Al[wave * 1024];
    u16* al1 = &Al[wave * 1024 + 512];
    u16* bl0 = &Bl[wave * 1024];
    u16* bl1 = &Bl[wave * 1024 + 512];

    f32x4 acc[4][4] = {};
    const int cm = (wave >> 1) * 4;
    const int cn = (wave & 1) * 4;

    for (int k0 = 0; k0 < K; k0 += 32) {
        gl_lds16(ag0 + k0, al0);
        gl_lds16(ag1 + k0, al1);
        gl_lds16(bg0 + k0, bl0);
        gl_lds16(bg1 + k0, bl1);
        __syncthreads();
        bf16x8 af[4], bv[4];
        #pragma unroll
        for (int mt = 0; mt < 4; ++mt) af[mt] = *(const bf16x8*)&Al[(cm + mt) * 512 + lane * 8];
        #pragma unroll
        for (int nt = 0; nt < 4; ++nt) bv[nt] = *(const bf16x8*)&Bl[(cn + nt) * 512 + lane * 8];
        #pragma unroll
        for (int mt = 0; mt < 4; ++mt)
            #pragma unroll
            for (int nt = 0; nt < 4; ++nt)
                acc[mt][nt] = __builtin_amdgcn_mfma_f32_16x16x32_bf16(
                    af[mt], bv[nt], acc[mt][nt], 0, 0, 0);
        __syncthreads();
    }

    const int wm = (wave >> 1) * 64, wn = (wave & 1) * 64;
    const int row0 = tm * 128 + wm + q * 4;
    const int col0 = tn * 128 + wn + r;
    if (CF32) {
        float* C = (float*)Cv;
        #pragma unroll
        for (int mt = 0; mt < 4; ++mt)
            #pragma unroll
            for (int i = 0; i < 4; ++i) {
                long rb = (long)(row0 + mt * 16 + i) * ldc + col0;
                #pragma unroll
                for (int nt = 0; nt < 4; ++nt)
                    C[rb + nt * 16] = acc[mt][nt][i];
            }
    } else {
        u16* C = (u16*)Cv;
        #pragma unroll
        for (int mt = 0; mt < 4; ++mt)
            #pragma unroll
            for (int i = 0; i < 4; ++i) {
                long rb = (long)(row0 + mt * 16 + i) * ldc + col0;
                #pragma unroll
                for (int nt = 0; nt < 4; ++nt)
                    C[rb + nt * 16] = f2bf(acc[mt][nt][i]);
            }
    }
}

// ---------------------------------------------------------------------------
// Flash attention, S^T formulation, 4-wave blocks with kv-parity split.
// Block = 256 threads (4 waves). q-tile 64: waves {0,2} handle q rows
// [q0, q0+32), waves {1,3} handle [q0+32, q0+64) (as two 16-col n-blocks).
// kv-tile 64. Waves 0,1 (parity 0) compute even kv tiles from buffer 0;
// waves 2,3 (parity 1) compute odd kv tiles from buffer 1. All 4 waves
// stage both buffers each iteration (20 chunks each of 80).
// Maxless exp2-domain softmax makes the parity split trivially mergeable
// at the end: O = O_e + O_o, l = l_e + l_o (one LDS exchange).
// LDS: 2 x (K 24KB + V 16KB) = 80KB -> 2 blocks/CU -> 8 waves/CU
// (vs previous 2-wave blocks at ~2-4 waves/CU, MfmaUtil 7.4%).
// ---------------------------------------------------------------------------
template<int C0, int C1>
__device__ __forceinline__ void stage_chunks(
    const u16* __restrict__ kvb, const u16* __restrict__ kpe,
    const u16* __restrict__ vt,
    u16* __restrict__ K0, u16* __restrict__ V0,
    u16* __restrict__ K1, u16* __restrict__ V1,
    int h, int t0, bool has1, int quad, int r)
{
    #pragma unroll
    for (int g = C0; g < C1; ++g) {
        const int b = (g >= 40) ? 1 : 0;
        if (b && !has1) continue;            // block-uniform guard
        const int c = b ? g - 40 : g;
        const int tk = t0 + b;
        u16* Kl = b ? K1 : K0;
        u16* Vl = b ? V1 : V0;
        if (c < 24) {
            const int mtk = c / 6, kc = c % 6;
            const int row = tk * 64 + mtk * 16 + r;
            const u16* src = (kc < 4)
                ? kvb + (size_t)row * 4096 + h * 256 + kc * 32 + quad * 8
                : kpe + (size_t)row * 64 + (kc - 4) * 32 + quad * 8;
            gl_lds16(src, &Kl[c * 512]);
        } else {
            const int cv = c - 24, mtd = cv >> 1, sc = cv & 1;
            const u16* src = vt + ((size_t)h * 128 + mtd * 16 + r) * 2048
                             + tk * 64 + sc * 32 + quad * 8;
            gl_lds16(src, &Vl[cv * 512]);
        }
    }
}

__device__ __forceinline__ void kv_tile_step(
    const u16* __restrict__ Kl, const u16* __restrict__ Vl,
    const bf16x8 (&Qf)[2][6], f32x4 (&Oacc)[8][2], float (&lsum)[2],
    int lane, int quad, int r, int kglob0, int qg0, int qg1, bool maskT)
{
    f32x4 Sacc[4][2];
    #pragma unroll
    for (int mtk = 0; mtk < 4; ++mtk) {
        Sacc[mtk][0] = (f32x4){0.f, 0.f, 0.f, 0.f};
        Sacc[mtk][1] = (f32x4){0.f, 0.f, 0.f, 0.f};
    }
    #pragma unroll
    for (int kc = 0; kc < 6; ++kc)
        #pragma unroll
        for (int mtk = 0; mtk < 4; ++mtk) {
            bf16x8 Ak = *(const bf16x8*)&Kl[(mtk * 6 + kc) * 512 + lane * 8];
            Sacc[mtk][0] = __builtin_amdgcn_mfma_f32_16x16x32_bf16(
                Ak, Qf[0][kc], Sacc[mtk][0], 0, 0, 0);
            Sacc[mtk][1] = __builtin_amdgcn_mfma_f32_16x16x32_bf16(
                Ak, Qf[1][kc], Sacc[mtk][1], 0, 0, 0);
        }
    #pragma unroll
    for (int kb = 0; kb < 4; ++kb) {
        s16x4 Pf[2];
        const int kb0 = kglob0 + kb * 16 + quad * 4;
        #pragma unroll
        for (int n = 0; n < 2; ++n) {
            const int qg = n ? qg1 : qg0;
            #pragma unroll
            for (int i = 0; i < 4; ++i) {
                float p = exp2f(Sacc[kb][n][i]);
                if (maskT && (kb0 + i > qg)) p = 0.f;
                lsum[n] += p;
                Pf[n][i] = (short)f2bf(p);
            }
        }
        #pragma unroll
        for (int mtd = 0; mtd < 8; ++mtd) {
            s16x4 Av = *(const s16x4*)&Vl[(mtd * 2 + (kb >> 1)) * 512
                         + ((kb & 1) * 2 + (quad >> 1)) * 128 + r * 8 + (quad & 1) * 4];
            Oacc[mtd][0] = mfma16(Av, Pf[0], Oacc[mtd][0]);
            Oacc[mtd][1] = mfma16(Av, Pf[1], Oacc[mtd][1]);
        }
    }
}

__global__ __launch_bounds__(256, 2)
void flash_attn(const u16* __restrict__ query, const u16* __restrict__ kvb,
                const u16* __restrict__ kpe, const u16* __restrict__ vt,
                u16* __restrict__ ao)
{
    const int tid = threadIdx.x;
    const int w = tid >> 6, lane = tid & 63;
    const int quad = lane >> 4, r = lane & 15;
    const int qhalf = w & 1;        // which 32-q half of the 64-q tile
    const int parity = w >> 1;      // which kv-tile parity this wave computes
    const int j = 31 - (int)blockIdx.x;   // heavy strips first
    const int h = blockIdx.y;
    const int q0 = j * 64;
    const int ntk = j + 1;          // 64-wide kv tiles up to the diagonal

    __shared__ __align__(16) u16 smem[40960];   // 80KB
    u16* K0 = smem;            // 24 chunks * 512 = 12288 u16 (24KB)
    u16* V0 = smem + 12288;    // 16 chunks * 512 =  8192 u16 (16KB)
    u16* K1 = smem + 20480;
    u16* V1 = smem + 32768;

    const int qg0 = q0 + qhalf * 32 + r;
    const int qg1 = qg0 + 16;

    bf16x8 Qf[2][6];
    #pragma unroll
    for (int n = 0; n < 2; ++n)
        #pragma unroll
        for (int kc = 0; kc < 6; ++kc)
            Qf[n][kc] = *(const bf16x8*)(query
                + ((size_t)h * S_LEN + q0 + qhalf * 32 + n * 16 + r) * QHEAD
                + kc * 32 + quad * 8);

    f32x4 Oacc[8][2];
    #pragma unroll
    for (int mtd = 0; mtd < 8; ++mtd) {
        Oacc[mtd][0] = (f32x4){0.f, 0.f, 0.f, 0.f};
        Oacc[mtd][1] = (f32x4){0.f, 0.f, 0.f, 0.f};
    }
    float lsum[2] = {0.f, 0.f};

    for (int t0 = 0; t0 < ntk; t0 += 2) {
        const bool has1 = (t0 + 1 < ntk);
        if (w == 0)
            stage_chunks<0, 20>(kvb, kpe, vt, K0, V0, K1, V1, h, t0, has1, quad, r);
        else if (w == 1)
            stage_chunks<20, 40>(kvb, kpe, vt, K0, V0, K1, V1, h, t0, has1, quad, r);
        else if (w == 2)
            stage_chunks<40, 60>(kvb, kpe, vt, K0, V0, K1, V1, h, t0, has1, quad, r);
        else
            stage_chunks<60, 80>(kvb, kpe, vt, K0, V0, K1, V1, h, t0, has1, quad, r);
        __syncthreads();
        const int tme = t0 + parity;
        if (tme < ntk)
            kv_tile_step(parity ? K1 : K0, parity ? V1 : V0, Qf, Oacc, lsum,
                         lane, quad, r, tme * 64, qg0, qg1, tme == ntk - 1);
        __syncthreads();
    }

    // Merge parity-1 partials into parity-0 (maxless softmax: plain sums).
    // Per lane: 16 f32x4 (Oacc) + 2 floats (lsum), padded to 68 floats.
    float* mf = (float*)smem;
    if (parity == 1) {
        float* base = mf + (size_t)(qhalf * 64 + lane) * 68;
        #pragma unroll
        for (int mtd = 0; mtd < 8; ++mtd)
            #pragma unroll
            for (int n = 0; n < 2; ++n)
                *(f32x4*)(base + (mtd * 2 + n) * 4) = Oacc[mtd][n];
        base[64] = lsum[0];
        base[65] = lsum[1];
    }
    __syncthreads();
    if (parity == 0) {
        float* base = mf + (size_t)(qhalf * 64 + lane) * 68;
        #pragma unroll
        for (int mtd = 0; mtd < 8; ++mtd)
            #pragma unroll
            for (int n = 0; n < 2; ++n)
                Oacc[mtd][n] += *(const f32x4*)(base + (mtd * 2 + n) * 4);
        lsum[0] += base[64];
        lsum[1] += base[65];

        #pragma unroll
        for (int n = 0; n < 2; ++n) {
            float l = lsum[n];
            l += __shfl_xor(l, 16, 64);
            l += __shfl_xor(l, 32, 64);
            float inv = 1.0f / l;
            const int qrow = q0 + qhalf * 32 + n * 16 + r;
            #pragma unroll
            for (int mtd = 0; mtd < 8; ++mtd) {
                ushort4 o;
                o.x = f2bf(Oacc[mtd][n][0] * inv);
                o.y = f2bf(Oacc[mtd][n][1] * inv);
                o.z = f2bf(Oacc[mtd][n][2] * inv);
                o.w = f2bf(Oacc[mtd][n][3] * inv);
                *(ushort4*)(ao + (size_t)qrow * 2048 + h * 128 + mtd * 16 + quad * 4) = o;
            }
        }
    }
}

// ---------------------------------------------------------------------------
__global__ __launch_bounds__(256)
void cvt_f32_bf16(const float4* __restrict__ in, ushort4* __restrict__ out, int n4)
{
    int i = blockIdx.x * 256 + threadIdx.x;
    if (i < n4) {
        float4 v = in[i];
        ushort4 o;
        o.x = f2bf(v.x); o.y = f2bf(v.y); o.z = f2bf(v.z); o.w = f2bf(v.w);
        out[i] = o;
    }
}

// in fp32 [K][N] -> out bf16 [Npad][K], rows >= N zero-filled.
__global__ __launch_bounds__(256)
void wtrans_k(const float* __restrict__ in, u16* __restrict__ out, int K, int N)
{
    __shared__ float tile[32][33];
    int k0 = blockIdx.x * 32, n0 = blockIdx.y * 32;
    int tx = threadIdx.x, ty = threadIdx.y;
    #pragma unroll
    for (int j = 0; j < 32; j += 8) {
        int n = n0 + tx;
        tile[ty + j][tx] = (n < N) ? in[(long)(k0 + ty + j) * N + n] : 0.0f;
    }
    __syncthreads();
    #pragma unroll
    for (int j = 0; j < 32; j += 8)
        out[(long)(n0 + ty + j) * K + k0 + tx] = f2bf(tile[tx][ty + j]);
}

// RMS norm in-place on first D cols of rows with stride ld.
__global__ __launch_bounds__(256)
void rmsnorm_k(u16* __restrict__ X, const float* __restrict__ w, int D, int ld)
{
    u16* row = X + (long)blockIdx.x * ld;
    const int tid = threadIdx.x;
    __shared__ float red[4];
    float sum = 0.f;
    for (int d = tid; d < D; d += 256) { float v = bf2f(row[d]); sum += v * v; }
    #pragma unroll
    for (int o = 32; o; o >>= 1) sum += __shfl_xor(sum, o, 64);
    if ((tid & 63) == 0) red[tid >> 6] = sum;
    __syncthreads();
    sum = red[0] + red[1] + red[2] + red[3];
    float scale = rsqrtf(sum / (float)D + EPS);
    for (int d = tid; d < D; d += 256)
        row[d] = f2bf(bf2f(row[d]) * scale * w[d]);
}

// qkv_a bf16 [S][2176] cols 1536.. = [c(512)|k_pe(64)] -> kv_cache fp32
// [S][576], c_norm bf16 [S][512], roped k_pe bf16 [S][64].
__global__ __launch_bounds__(256)
void kvcache_k(const u16* __restrict__ qkv, const float* __restrict__ ln,
               const int* __restrict__ pos_ids, const float* __restrict__ cosb,
               const float* __restrict__ sinb, float* __restrict__ kvout,
               u16* __restrict__ cnb, u16* __restrict__ kpe)
{
    const int s = blockIdx.x, tid = threadIdx.x;
    const u16* row = qkv + (long)s * 2176 + 1536;
    __shared__ float red[4];
    float sum = 0.f;
    for (int d = tid; d < 512; d += 256) { float v = bf2f(row[d]); sum += v * v; }
    #pragma unroll
    for (int o = 32; o; o >>= 1) sum += __shfl_xor(sum, o, 64);
    if ((tid & 63) == 0) red[tid >> 6] = sum;
    __syncthreads();
    sum = red[0] + red[1] + red[2] + red[3];
    float scale = rsqrtf(sum / 512.f + EPS);
    for (int d = tid; d < 512; d += 256) {
        float v = bf2f(row[d]) * scale * ln[d];
        kvout[(long)s * 576 + d] = v;
        cnb[(long)s * 512 + d] = f2bf(v);
    }
    if (tid < 32) {
        int p = pos_ids[s];
        float x0 = bf2f(row[512 + 2 * tid]);
        float x1 = bf2f(row[512 + 2 * tid + 1]);
        float c1 = cosb[p * 64 + tid], s1 = sinb[p * 64 + tid];
        float c2 = cosb[p * 64 + 32 + tid], s2 = sinb[p * 64 + 32 + tid];
        float lo = x0 * c1 - x1 * s1;
        float hi = x1 * c2 + x0 * s2;
        kvout[(long)s * 576 + 512 + tid] = lo;
        kvout[(long)s * 576 + 544 + tid] = hi;
        kpe[(long)s * 64 + tid] = f2bf(lo);
        kpe[(long)s * 64 + 32 + tid] = f2bf(hi);
    }
}

// q bf16 [S][3072] -> query bf16 [H][S][192], rope on last 64 dims,
// all values pre-scaled by SCALE*log2(e) for exp2-domain softmax.
__global__ __launch_bounds__(256)
void qrope_k(const u16* __restrict__ qb, const int* __restrict__ pos_ids,
             const float* __restrict__ cosb, const float* __restrict__ sinb,
             u16* __restrict__ query)
{
    const int s = blockIdx.x, tid = threadIdx.x;
    const u16* row = qb + (long)s * 3072;
    {   // nope part: 16 heads x 16 chunks of 8, scaled
        int h = tid >> 4, c = tid & 15;
        const u16* src = &row[h * QHEAD + c * 8];
        u16* dst = &query[((long)(h * S_LEN + s)) * QHEAD + c * 8];
        ushort4 a = *(const ushort4*)src;
        ushort4 b = *(const ushort4*)(src + 4);
        ushort4 oa, ob;
        oa.x = f2bf(bf2f(a.x) * QSCALE_LOG2E); oa.y = f2bf(bf2f(a.y) * QSCALE_LOG2E);
        oa.z = f2bf(bf2f(a.z) * QSCALE_LOG2E); oa.w = f2bf(bf2f(a.w) * QSCALE_LOG2E);
        ob.x = f2bf(bf2f(b.x) * QSCALE_LOG2E); ob.y = f2bf(bf2f(b.y) * QSCALE_LOG2E);
        ob.z = f2bf(bf2f(b.z) * QSCALE_LOG2E); ob.w = f2bf(bf2f(b.w) * QSCALE_LOG2E);
        *(ushort4*)dst = oa;
        *(ushort4*)(dst + 4) = ob;
    }
    int p = pos_ids[s];
    for (int idx = tid; idx < 512; idx += 256) {
        int h = idx >> 5, i = idx & 31;
        float x0 = bf2f(row[h * QHEAD + 128 + 2 * i]);
        float x1 = bf2f(row[h * QHEAD + 128 + 2 * i + 1]);
        float c1 = cosb[p * 64 + i], s1 = sinb[p * 64 + i];
        float c2 = cosb[p * 64 + 32 + i], s2 = sinb[p * 64 + 32 + i];
        u16* qr = query + ((long)(h * S_LEN + s)) * QHEAD;
        qr[128 + i] = f2bf((x0 * c1 - x1 * s1) * QSCALE_LOG2E);
        qr[160 + i] = f2bf((x1 * c2 + x0 * s2) * QSCALE_LOG2E);
    }
}

// kv bf16 [S][4096] value part -> vt bf16 [H*128][S] (transposed)
__global__ __launch_bounds__(256)
void vtrans_k(const u16* __restrict__ kv, u16* __restrict__ vt)
{
    __shared__ u16 tile[32][33];
    int s0 = blockIdx.x * 32, d0 = blockIdx.y * 32, h = blockIdx.z;
    int tx = threadIdx.x, ty = threadIdx.y;
    #pragma unroll
    for (int j = 0; j < 32; j += 8)
        tile[ty + j][tx] = kv[(long)(s0 + ty + j) * 4096 + h * 256 + 128 + d0 + tx];
    __syncthreads();
    #pragma unroll
    for (int j = 0; j < 32; j += 8)
        vt[(long)(h * 128 + d0 + ty + j) * S_LEN + s0 + tx] = tile[tx][ty + j];
}

// ---------------------------------------------------------------------------
extern "C" void kernel_launch(void* const* d_in, const int* in_sizes, int n_in,
                              void* d_out, int out_size, void* d_ws, size_t ws_size,
                              hipStream_t stream)
{
    const float* x      = (const float*)d_in[0];
    const int*   posid  = (const int*)d_in[2];
    const float* cosb   = (const float*)d_in[3];
    const float* sinb   = (const float*)d_in[4];
    const float* q_a_w  = (const float*)d_in[5];
    const float* q_a_ln = (const float*)d_in[6];
    const float* q_b_w  = (const float*)d_in[7];
    const float* kv_a_w = (const float*)d_in[8];
    const float* kv_a_ln= (const float*)d_in[9];
    const float* kv_b_w = (const float*)d_in[10];
    const float* o_w    = (const float*)d_in[11];

    float* out    = (float*)d_out;
    float* kv_out = out + (size_t)2048 * 2048;

    char* ws = (char*)d_ws;
    size_t off = 0;
    auto alloc = [&](size_t bytes) { char* p = ws + off; off += (bytes + 255) & ~(size_t)255; return p; };
    u16* xb    = (u16*)alloc(2048ULL * 2048 * 2);
    u16* W1    = (u16*)alloc(2176ULL * 2048 * 2);   // [q_a^T ; kv_a^T(pad 640)]
    u16* qbwt  = (u16*)alloc(3072ULL * 1536 * 2);
    u16* kvbwt = (u16*)alloc(4096ULL * 512 * 2);
    u16* owt   = (u16*)alloc(2048ULL * 2048 * 2);
    u16* qkv_a = (u16*)alloc(2048ULL * 2176 * 2);   // [q_a(1536) | ckv(640)]
    u16* qbuf  = (u16*)alloc(2048ULL * 3072 * 2);
    u16* query = (u16*)alloc(16ULL * 2048 * 192 * 2);
    u16* cnb   = (u16*)alloc(2048ULL * 512 * 2);
    u16* kpe   = (u16*)alloc(2048ULL * 64 * 2);
    u16* kvbuf = (u16*)alloc(2048ULL * 4096 * 2);
    u16* vt    = (u16*)alloc(16ULL * 128 * 2048 * 2);
    u16* ao    = (u16*)alloc(2048ULL * 2048 * 2);
    (void)ws_size; (void)in_sizes; (void)n_in; (void)out_size;

    dim3 blk(256);
    dim3 tblk(32, 8);

    // 0) conversions / weight transposes
    cvt_f32_bf16<<<dim3(4096), blk, 0, stream>>>((const float4*)x, (ushort4*)xb, 2048 * 2048 / 4);
    wtrans_k<<<dim3(64, 48),  tblk, 0, stream>>>(q_a_w,  W1,                    2048, 1536);
    wtrans_k<<<dim3(64, 20),  tblk, 0, stream>>>(kv_a_w, W1 + 1536ULL * 2048,   2048, 576);
    wtrans_k<<<dim3(48, 96),  tblk, 0, stream>>>(q_b_w,  qbwt,  1536, 3072);
    wtrans_k<<<dim3(16, 128), tblk, 0, stream>>>(kv_b_w, kvbwt, 512,  4096);
    wtrans_k<<<dim3(64, 64),  tblk, 0, stream>>>(o_w,    owt,   2048, 2048);

    // 1) [q_a | ckv] = x @ [q_a_w | kv_a_w]  (merged, N=2176)
    gemm_bt<0><<<dim3(17, 16), blk, 0, stream>>>(xb, W1, qkv_a, 2048, 2048, 2048, 2176);
    rmsnorm_k<<<dim3(2048), blk, 0, stream>>>(qkv_a, q_a_ln, 1536, 2176);
    kvcache_k<<<dim3(2048), blk, 0, stream>>>(qkv_a, kv_a_ln, posid, cosb, sinb, kv_out, cnb, kpe);

    // 2) q = q_a_norm @ q_b_w ; rope + relayout (+ exp2-domain pre-scale)
    gemm_bt<0><<<dim3(24, 16), blk, 0, stream>>>(qkv_a, qbwt, qbuf, 1536, 2176, 1536, 3072);
    qrope_k<<<dim3(2048), blk, 0, stream>>>(qbuf, posid, cosb, sinb, query);

    // 3) kv = c_norm @ kv_b_w ; transpose value
    gemm_bt<0><<<dim3(32, 16), blk, 0, stream>>>(cnb, kvbwt, kvbuf, 512, 512, 512, 4096);
    vtrans_k<<<dim3(64, 4, 16), tblk, 0, stream>>>(kvbuf, vt);

    // 4) fused flash attention (S^T form, parity-split) -> ao bf16 [S][H*128]
    flash_attn<<<dim3(32, 16), dim3(256), 0, stream>>>(query, kvbuf, kpe, vt, ao);

    // 5) out = ao @ o_w (fp32)
    gemm_bt<1><<<dim3(16, 16), blk, 0, stream>>>(ao, owt, out, 2048, 2048, 2048, 2048);
}

// Round 2
// 453.851 us; speedup vs baseline: 1.0969x; 1.0054x over previous
//
#include <hip/hip_runtime.h>

typedef unsigned short u16;
typedef __bf16 bf16x8 __attribute__((ext_vector_type(8)));
typedef short s16x4 __attribute__((ext_vector_type(4)));
typedef float f32x4 __attribute__((ext_vector_type(4)));

#define S_LEN 2048
#define NHEAD 16
#define QHEAD 192
#define EPS 1e-6f
#define ATTN_SCALE 0.07216878364870323f   /* 192^-0.5 */
#define QSCALE_LOG2E 0.10412011228586118f /* ATTN_SCALE * log2(e) */

__device__ __forceinline__ u16 f2bf(float f) {
    unsigned u = __builtin_bit_cast(unsigned, f);
    u = (u + 0x7FFFu + ((u >> 16) & 1u)) >> 16;
    return (u16)u;
}
__device__ __forceinline__ float bf2f(u16 h) {
    unsigned u = ((unsigned)h) << 16;
    return __builtin_bit_cast(float, u);
}

__device__ __forceinline__ void gl_lds16(const u16* g, u16* l) {
    __builtin_amdgcn_global_load_lds(
        (const __attribute__((address_space(1))) unsigned int*)g,
        (__attribute__((address_space(3))) unsigned int*)l,
        16, 0, 0);
}

#if defined(__has_builtin) && __has_builtin(__builtin_amdgcn_mfma_f32_16x16x16bf16_1k)
__device__ __forceinline__ f32x4 mfma16(s16x4 a, s16x4 b, f32x4 c) {
    return __builtin_amdgcn_mfma_f32_16x16x16bf16_1k(a, b, c, 0, 0, 0);
}
#else
__device__ __forceinline__ f32x4 mfma16(s16x4 a, s16x4 b, f32x4 c) {
    asm volatile("v_mfma_f32_16x16x16_bf16 %0, %1, %2, %0"
                 : "+v"(c) : "v"(a), "v"(b));
    return c;
}
#endif

// ---------------------------------------------------------------------------
// bf16 GEMM:  C[M][N] = A[M][K] @ Bt[N][K]^T   (unchanged)
// ---------------------------------------------------------------------------
template <int CF32>
__global__ __launch_bounds__(256, 2)
void gemm_bt(const u16* __restrict__ A, const u16* __restrict__ B,
             void* __restrict__ Cv, int K, int lda, int ldb, int ldc)
{
    const int tid = threadIdx.x;
    const int wave = tid >> 6, lane = tid & 63;
    const int q = lane >> 4, r = lane & 15;
    const int tm = blockIdx.y, tn = blockIdx.x;

    __shared__ __align__(16) u16 Al[128 * 32];
    __shared__ __align__(16) u16 Bl[128 * 32];

    const int lr = lane & 15;
    const int lc = (lane >> 4) * 8;
    const u16* ag0 = A + (long)(tm * 128 + wave * 32 + lr) * lda + lc;
    const u16* ag1 = ag0 + 16 * (long)lda;
    const u16* bg0 = B + (long)(tn * 128 + wave * 32 + lr) * ldb + lc;
    const u16* bg1 = bg0 + 16 * (long)ldb;
    u16* al0 = &Al[wave * 1024];
    u16* al1 = &Al[wave * 1024 + 512];
    u16* bl0 = &Bl[wave * 1024];
    u16* bl1 = &Bl[wave * 1024 + 512];

    f32x4 acc[4][4] = {};
    const int cm = (wave >> 1) * 4;
    const int cn = (wave & 1) * 4;

    for (int k0 = 0; k0 < K; k0 += 32) {
        gl_lds16(ag0 + k0, al0);
        gl_lds16(ag1 + k0, al1);
        gl_lds16(bg0 + k0, bl0);
        gl_lds16(bg1 + k0, bl1);
        __syncthreads();
        bf16x8 af[4], bv[4];
        #pragma unroll
        for (int mt = 0; mt < 4; ++mt) af[mt] = *(const bf16x8*)&Al[(cm + mt) * 512 + lane * 8];
        #pragma unroll
        for (int nt = 0; nt < 4; ++nt) bv[nt] = *(const bf16x8*)&Bl[(cn + nt) * 512 + lane * 8];
        #pragma unroll
        for (int mt = 0; mt < 4; ++mt)
            #pragma unroll
            for (int nt = 0; nt < 4; ++nt)
                acc[mt][nt] = __builtin_amdgcn_mfma_f32_16x16x32_bf16(
                    af[mt], bv[nt], acc[mt][nt], 0, 0, 0);
        __syncthreads();
    }

    const int wm = (wave >> 1) * 64, wn = (wave & 1) * 64;
    const int row0 = tm * 128 + wm + q * 4;
    const int col0 = tn * 128 + wn + r;
    if (CF32) {
        float* C = (float*)Cv;
        #pragma unroll
        for (int mt = 0; mt < 4; ++mt)
            #pragma unroll
            for (int i = 0; i < 4; ++i) {
                long rb = (long)(row0 + mt * 16 + i) * ldc + col0;
                #pragma unroll
                for (int nt = 0; nt < 4; ++nt)
                    C[rb + nt * 16] = acc[mt][nt][i];
            }
    } else {
        u16* C = (u16*)Cv;
        #pragma unroll
        for (int mt = 0; mt < 4; ++mt)
            #pragma unroll
            for (int i = 0; i < 4; ++i) {
                long rb = (long)(row0 + mt * 16 + i) * ldc + col0;
                #pragma unroll
                for (int nt = 0; nt < 4; ++nt)
                    C[rb + nt * 16] = f2bf(acc[mt][nt][i]);
            }
    }
}

// ---------------------------------------------------------------------------
// Flash attention, S^T formulation, 4-wave blocks with kv-parity split.
// Block = 256 threads (4 waves). q-tile 64: waves {0,2} handle q rows
// [q0, q0+32), waves {1,3} handle [q0+32, q0+64) (as two 16-col n-blocks).
// kv-tile 64. Waves 0,1 (parity 0) compute even kv tiles from buffer 0;
// waves 2,3 (parity 1) compute odd kv tiles from buffer 1.
// Maxless exp2-domain softmax, mergeable at the end (O=O_e+O_o, l=l_e+l_o).
// LDS: 2 x (K 24KB + V 16KB) = 80KB -> 2 blocks/CU -> 8 waves/CU.
//
// Load balance: grid is 1D 512 = 2 blocks/CU, ALL resident at t=0 (no queue
// rebalancing). Blocks b and b+256 land on the same CU (dXCD=0 mod 8,
// dCU=0 mod 32). Map [0,256) -> heavy strips j=16..31, [256,512) -> light
// strips j=0..15 with complementary pairing: work(b)+work(b+256) =
// (32-t) + (t+1) = 33 tiles for every CU (was: identical strips paired,
// 64 vs 2 -> ~1.9x tail).
// ---------------------------------------------------------------------------
template<int C0, int C1>
__device__ __forceinline__ void stage_chunks(
    const u16* __restrict__ kvb, const u16* __restrict__ kpe,
    const u16* __restrict__ vt,
    u16* __restrict__ K0, u16* __restrict__ V0,
    u16* __restrict__ K1, u16* __restrict__ V1,
    int h, int t0, bool has1, int quad, int r)
{
    #pragma unroll
    for (int g = C0; g < C1; ++g) {
        const int b = (g >= 40) ? 1 : 0;
        if (b && !has1) continue;            // block-uniform guard
        const int c = b ? g - 40 : g;
        const int tk = t0 + b;
        u16* Kl = b ? K1 : K0;
        u16* Vl = b ? V1 : V0;
        if (c < 24) {
            const int mtk = c / 6, kc = c % 6;
            const int row = tk * 64 + mtk * 16 + r;
            const u16* src = (kc < 4)
                ? kvb + (size_t)row * 4096 + h * 256 + kc * 32 + quad * 8
                : kpe + (size_t)row * 64 + (kc - 4) * 32 + quad * 8;
            gl_lds16(src, &Kl[c * 512]);
        } else {
            const int cv = c - 24, mtd = cv >> 1, sc = cv & 1;
            const u16* src = vt + ((size_t)h * 128 + mtd * 16 + r) * 2048
                             + tk * 64 + sc * 32 + quad * 8;
            gl_lds16(src, &Vl[cv * 512]);
        }
    }
}

__device__ __forceinline__ void kv_tile_step(
    const u16* __restrict__ Kl, const u16* __restrict__ Vl,
    const bf16x8 (&Qf)[2][6], f32x4 (&Oacc)[8][2], float (&lsum)[2],
    int lane, int quad, int r, int kglob0, int qg0, int qg1, bool maskT)
{
    f32x4 Sacc[4][2];
    #pragma unroll
    for (int mtk = 0; mtk < 4; ++mtk) {
        Sacc[mtk][0] = (f32x4){0.f, 0.f, 0.f, 0.f};
        Sacc[mtk][1] = (f32x4){0.f, 0.f, 0.f, 0.f};
    }
    #pragma unroll
    for (int kc = 0; kc < 6; ++kc)
        #pragma unroll
        for (int mtk = 0; mtk < 4; ++mtk) {
            bf16x8 Ak = *(const bf16x8*)&Kl[(mtk * 6 + kc) * 512 + lane * 8];
            Sacc[mtk][0] = __builtin_amdgcn_mfma_f32_16x16x32_bf16(
                Ak, Qf[0][kc], Sacc[mtk][0], 0, 0, 0);
            Sacc[mtk][1] = __builtin_amdgcn_mfma_f32_16x16x32_bf16(
                Ak, Qf[1][kc], Sacc[mtk][1], 0, 0, 0);
        }
    #pragma unroll
    for (int kb = 0; kb < 4; ++kb) {
        s16x4 Pf[2];
        const int kb0 = kglob0 + kb * 16 + quad * 4;
        #pragma unroll
        for (int n = 0; n < 2; ++n) {
            const int qg = n ? qg1 : qg0;
            #pragma unroll
            for (int i = 0; i < 4; ++i) {
                float p = exp2f(Sacc[kb][n][i]);
                if (maskT && (kb0 + i > qg)) p = 0.f;
                lsum[n] += p;
                Pf[n][i] = (short)f2bf(p);
            }
        }
        #pragma unroll
        for (int mtd = 0; mtd < 8; ++mtd) {
            s16x4 Av = *(const s16x4*)&Vl[(mtd * 2 + (kb >> 1)) * 512
                         + ((kb & 1) * 2 + (quad >> 1)) * 128 + r * 8 + (quad & 1) * 4];
            Oacc[mtd][0] = mfma16(Av, Pf[0], Oacc[mtd][0]);
            Oacc[mtd][1] = mfma16(Av, Pf[1], Oacc[mtd][1]);
        }
    }
}

__global__ __launch_bounds__(256, 2)
void flash_attn(const u16* __restrict__ query, const u16* __restrict__ kvb,
                const u16* __restrict__ kpe, const u16* __restrict__ vt,
                u16* __restrict__ ao)
{
    const int tid = threadIdx.x;
    const int w = tid >> 6, lane = tid & 63;
    const int quad = lane >> 4, r = lane & 15;
    const int qhalf = w & 1;        // which 32-q half of the 64-q tile
    const int parity = w >> 1;      // which kv-tile parity this wave computes

    // Complementary work pairing (see header comment).
    const int bid = (int)blockIdx.x;
    const int i = bid & 255;
    const int t = i >> 4;
    const int h = i & 15;
    const int j = (bid < 256) ? (31 - t) : t;

    const int q0 = j * 64;
    const int ntk = j + 1;          // 64-wide kv tiles up to the diagonal

    __shared__ __align__(16) u16 smem[40960];   // 80KB
    u16* K0 = smem;            // 24 chunks * 512 = 12288 u16 (24KB)
    u16* V0 = smem + 12288;    // 16 chunks * 512 =  8192 u16 (16KB)
    u16* K1 = smem + 20480;
    u16* V1 = smem + 32768;

    const int qg0 = q0 + qhalf * 32 + r;
    const int qg1 = qg0 + 16;

    bf16x8 Qf[2][6];
    #pragma unroll
    for (int n = 0; n < 2; ++n)
        #pragma unroll
        for (int kc = 0; kc < 6; ++kc)
            Qf[n][kc] = *(const bf16x8*)(query
                + ((size_t)h * S_LEN + q0 + qhalf * 32 + n * 16 + r) * QHEAD
                + kc * 32 + quad * 8);

    f32x4 Oacc[8][2];
    #pragma unroll
    for (int mtd = 0; mtd < 8; ++mtd) {
        Oacc[mtd][0] = (f32x4){0.f, 0.f, 0.f, 0.f};
        Oacc[mtd][1] = (f32x4){0.f, 0.f, 0.f, 0.f};
    }
    float lsum[2] = {0.f, 0.f};

    for (int t0 = 0; t0 < ntk; t0 += 2) {
        const bool has1 = (t0 + 1 < ntk);
        if (w == 0)
            stage_chunks<0, 20>(kvb, kpe, vt, K0, V0, K1, V1, h, t0, has1, quad, r);
        else if (w == 1)
            stage_chunks<20, 40>(kvb, kpe, vt, K0, V0, K1, V1, h, t0, has1, quad, r);
        else if (w == 2)
            stage_chunks<40, 60>(kvb, kpe, vt, K0, V0, K1, V1, h, t0, has1, quad, r);
        else
            stage_chunks<60, 80>(kvb, kpe, vt, K0, V0, K1, V1, h, t0, has1, quad, r);
        __syncthreads();
        const int tme = t0 + parity;
        if (tme < ntk)
            kv_tile_step(parity ? K1 : K0, parity ? V1 : V0, Qf, Oacc, lsum,
                         lane, quad, r, tme * 64, qg0, qg1, tme == ntk - 1);
        __syncthreads();
    }

    // Merge parity-1 partials into parity-0 (maxless softmax: plain sums).
    // Per lane: 16 f32x4 (Oacc) + 2 floats (lsum), padded to 68 floats.
    float* mf = (float*)smem;
    if (parity == 1) {
        float* base = mf + (size_t)(qhalf * 64 + lane) * 68;
        #pragma unroll
        for (int mtd = 0; mtd < 8; ++mtd)
            #pragma unroll
            for (int n = 0; n < 2; ++n)
                *(f32x4*)(base + (mtd * 2 + n) * 4) = Oacc[mtd][n];
        base[64] = lsum[0];
        base[65] = lsum[1];
    }
    __syncthreads();
    if (parity == 0) {
        float* base = mf + (size_t)(qhalf * 64 + lane) * 68;
        #pragma unroll
        for (int mtd = 0; mtd < 8; ++mtd)
            #pragma unroll
            for (int n = 0; n < 2; ++n)
                Oacc[mtd][n] += *(const f32x4*)(base + (mtd * 2 + n) * 4);
        lsum[0] += base[64];
        lsum[1] += base[65];

        #pragma unroll
        for (int n = 0; n < 2; ++n) {
            float l = lsum[n];
            l += __shfl_xor(l, 16, 64);
            l += __shfl_xor(l, 32, 64);
            float inv = 1.0f / l;
            const int qrow = q0 + qhalf * 32 + n * 16 + r;
            #pragma unroll
            for (int mtd = 0; mtd < 8; ++mtd) {
                ushort4 o;
                o.x = f2bf(Oacc[mtd][n][0] * inv);
                o.y = f2bf(Oacc[mtd][n][1] * inv);
                o.z = f2bf(Oacc[mtd][n][2] * inv);
                o.w = f2bf(Oacc[mtd][n][3] * inv);
                *(ushort4*)(ao + (size_t)qrow * 2048 + h * 128 + mtd * 16 + quad * 4) = o;
            }
        }
    }
}

// ---------------------------------------------------------------------------
__global__ __launch_bounds__(256)
void cvt_f32_bf16(const float4* __restrict__ in, ushort4* __restrict__ out, int n4)
{
    int i = blockIdx.x * 256 + threadIdx.x;
    if (i < n4) {
        float4 v = in[i];
        ushort4 o;
        o.x = f2bf(v.x); o.y = f2bf(v.y); o.z = f2bf(v.z); o.w = f2bf(v.w);
        out[i] = o;
    }
}

// in fp32 [K][N] -> out bf16 [Npad][K], rows >= N zero-filled.
__global__ __launch_bounds__(256)
void wtrans_k(const float* __restrict__ in, u16* __restrict__ out, int K, int N)
{
    __shared__ float tile[32][33];
    int k0 = blockIdx.x * 32, n0 = blockIdx.y * 32;
    int tx = threadIdx.x, ty = threadIdx.y;
    #pragma unroll
    for (int j = 0; j < 32; j += 8) {
        int n = n0 + tx;
        tile[ty + j][tx] = (n < N) ? in[(long)(k0 + ty + j) * N + n] : 0.0f;
    }
    __syncthreads();
    #pragma unroll
    for (int j = 0; j < 32; j += 8)
        out[(long)(n0 + ty + j) * K + k0 + tx] = f2bf(tile[tx][ty + j]);
}

// RMS norm in-place on first D cols of rows with stride ld.
__global__ __launch_bounds__(256)
void rmsnorm_k(u16* __restrict__ X, const float* __restrict__ w, int D, int ld)
{
    u16* row = X + (long)blockIdx.x * ld;
    const int tid = threadIdx.x;
    __shared__ float red[4];
    float sum = 0.f;
    for (int d = tid; d < D; d += 256) { float v = bf2f(row[d]); sum += v * v; }
    #pragma unroll
    for (int o = 32; o; o >>= 1) sum += __shfl_xor(sum, o, 64);
    if ((tid & 63) == 0) red[tid >> 6] = sum;
    __syncthreads();
    sum = red[0] + red[1] + red[2] + red[3];
    float scale = rsqrtf(sum / (float)D + EPS);
    for (int d = tid; d < D; d += 256)
        row[d] = f2bf(bf2f(row[d]) * scale * w[d]);
}

// qkv_a bf16 [S][2176] cols 1536.. = [c(512)|k_pe(64)] -> kv_cache fp32
// [S][576], c_norm bf16 [S][512], roped k_pe bf16 [S][64].
__global__ __launch_bounds__(256)
void kvcache_k(const u16* __restrict__ qkv, const float* __restrict__ ln,
               const int* __restrict__ pos_ids, const float* __restrict__ cosb,
               const float* __restrict__ sinb, float* __restrict__ kvout,
               u16* __restrict__ cnb, u16* __restrict__ kpe)
{
    const int s = blockIdx.x, tid = threadIdx.x;
    const u16* row = qkv + (long)s * 2176 + 1536;
    __shared__ float red[4];
    float sum = 0.f;
    for (int d = tid; d < 512; d += 256) { float v = bf2f(row[d]); sum += v * v; }
    #pragma unroll
    for (int o = 32; o; o >>= 1) sum += __shfl_xor(sum, o, 64);
    if ((tid & 63) == 0) red[tid >> 6] = sum;
    __syncthreads();
    sum = red[0] + red[1] + red[2] + red[3];
    float scale = rsqrtf(sum / 512.f + EPS);
    for (int d = tid; d < 512; d += 256) {
        float v = bf2f(row[d]) * scale * ln[d];
        kvout[(long)s * 576 + d] = v;
        cnb[(long)s * 512 + d] = f2bf(v);
    }
    if (tid < 32) {
        int p = pos_ids[s];
        float x0 = bf2f(row[512 + 2 * tid]);
        float x1 = bf2f(row[512 + 2 * tid + 1]);
        float c1 = cosb[p * 64 + tid], s1 = sinb[p * 64 + tid];
        float c2 = cosb[p * 64 + 32 + tid], s2 = sinb[p * 64 + 32 + tid];
        float lo = x0 * c1 - x1 * s1;
        float hi = x1 * c2 + x0 * s2;
        kvout[(long)s * 576 + 512 + tid] = lo;
        kvout[(long)s * 576 + 544 + tid] = hi;
        kpe[(long)s * 64 + tid] = f2bf(lo);
        kpe[(long)s * 64 + 32 + tid] = f2bf(hi);
    }
}

// q bf16 [S][3072] -> query bf16 [H][S][192], rope on last 64 dims,
// all values pre-scaled by SCALE*log2(e) for exp2-domain softmax.
__global__ __launch_bounds__(256)
void qrope_k(const u16* __restrict__ qb, const int* __restrict__ pos_ids,
             const float* __restrict__ cosb, const float* __restrict__ sinb,
             u16* __restrict__ query)
{
    const int s = blockIdx.x, tid = threadIdx.x;
    const u16* row = qb + (long)s * 3072;
    {   // nope part: 16 heads x 16 chunks of 8, scaled
        int h = tid >> 4, c = tid & 15;
        const u16* src = &row[h * QHEAD + c * 8];
        u16* dst = &query[((long)(h * S_LEN + s)) * QHEAD + c * 8];
        ushort4 a = *(const ushort4*)src;
        ushort4 b = *(const ushort4*)(src + 4);
        ushort4 oa, ob;
        oa.x = f2bf(bf2f(a.x) * QSCALE_LOG2E); oa.y = f2bf(bf2f(a.y) * QSCALE_LOG2E);
        oa.z = f2bf(bf2f(a.z) * QSCALE_LOG2E); oa.w = f2bf(bf2f(a.w) * QSCALE_LOG2E);
        ob.x = f2bf(bf2f(b.x) * QSCALE_LOG2E); ob.y = f2bf(bf2f(b.y) * QSCALE_LOG2E);
        ob.z = f2bf(bf2f(b.z) * QSCALE_LOG2E); ob.w = f2bf(bf2f(b.w) * QSCALE_LOG2E);
        *(ushort4*)dst = oa;
        *(ushort4*)(dst + 4) = ob;
    }
    int p = pos_ids[s];
    for (int idx = tid; idx < 512; idx += 256) {
        int h = idx >> 5, i = idx & 31;
        float x0 = bf2f(row[h * QHEAD + 128 + 2 * i]);
        float x1 = bf2f(row[h * QHEAD + 128 + 2 * i + 1]);
        float c1 = cosb[p * 64 + i], s1 = sinb[p * 64 + i];
        float c2 = cosb[p * 64 + 32 + i], s2 = sinb[p * 64 + 32 + i];
        u16* qr = query + ((long)(h * S_LEN + s)) * QHEAD;
        qr[128 + i] = f2bf((x0 * c1 - x1 * s1) * QSCALE_LOG2E);
        qr[160 + i] = f2bf((x1 * c2 + x0 * s2) * QSCALE_LOG2E);
    }
}

// kv bf16 [S][4096] value part -> vt bf16 [H*128][S] (transposed)
__global__ __launch_bounds__(256)
void vtrans_k(const u16* __restrict__ kv, u16* __restrict__ vt)
{
    __shared__ u16 tile[32][33];
    int s0 = blockIdx.x * 32, d0 = blockIdx.y * 32, h = blockIdx.z;
    int tx = threadIdx.x, ty = threadIdx.y;
    #pragma unroll
    for (int j = 0; j < 32; j += 8)
        tile[ty + j][tx] = kv[(long)(s0 + ty + j) * 4096 + h * 256 + 128 + d0 + tx];
    __syncthreads();
    #pragma unroll
    for (int j = 0; j < 32; j += 8)
        vt[(long)(h * 128 + d0 + ty + j) * S_LEN + s0 + tx] = tile[tx][ty + j];
}

// ---------------------------------------------------------------------------
extern "C" void kernel_launch(void* const* d_in, const int* in_sizes, int n_in,
                              void* d_out, int out_size, void* d_ws, size_t ws_size,
                              hipStream_t stream)
{
    const float* x      = (const float*)d_in[0];
    const int*   posid  = (const int*)d_in[2];
    const float* cosb   = (const float*)d_in[3];
    const float* sinb   = (const float*)d_in[4];
    const float* q_a_w  = (const float*)d_in[5];
    const float* q_a_ln = (const float*)d_in[6];
    const float* q_b_w  = (const float*)d_in[7];
    const float* kv_a_w = (const float*)d_in[8];
    const float* kv_a_ln= (const float*)d_in[9];
    const float* kv_b_w = (const float*)d_in[10];
    const float* o_w    = (const float*)d_in[11];

    float* out    = (float*)d_out;
    float* kv_out = out + (size_t)2048 * 2048;

    char* ws = (char*)d_ws;
    size_t off = 0;
    auto alloc = [&](size_t bytes) { char* p = ws + off; off += (bytes + 255) & ~(size_t)255; return p; };
    u16* xb    = (u16*)alloc(2048ULL * 2048 * 2);
    u16* W1    = (u16*)alloc(2176ULL * 2048 * 2);   // [q_a^T ; kv_a^T(pad 640)]
    u16* qbwt  = (u16*)alloc(3072ULL * 1536 * 2);
    u16* kvbwt = (u16*)alloc(4096ULL * 512 * 2);
    u16* owt   = (u16*)alloc(2048ULL * 2048 * 2);
    u16* qkv_a = (u16*)alloc(2048ULL * 2176 * 2);   // [q_a(1536) | ckv(640)]
    u16* qbuf  = (u16*)alloc(2048ULL * 3072 * 2);
    u16* query = (u16*)alloc(16ULL * 2048 * 192 * 2);
    u16* cnb   = (u16*)alloc(2048ULL * 512 * 2);
    u16* kpe   = (u16*)alloc(2048ULL * 64 * 2);
    u16* kvbuf = (u16*)alloc(2048ULL * 4096 * 2);
    u16* vt    = (u16*)alloc(16ULL * 128 * 2048 * 2);
    u16* ao    = (u16*)alloc(2048ULL * 2048 * 2);
    (void)ws_size; (void)in_sizes; (void)n_in; (void)out_size;

    dim3 blk(256);
    dim3 tblk(32, 8);

    // 0) conversions / weight transposes
    cvt_f32_bf16<<<dim3(4096), blk, 0, stream>>>((const float4*)x, (ushort4*)xb, 2048 * 2048 / 4);
    wtrans_k<<<dim3(64, 48),  tblk, 0, stream>>>(q_a_w,  W1,                    2048, 1536);
    wtrans_k<<<dim3(64, 20),  tblk, 0, stream>>>(kv_a_w, W1 + 1536ULL * 2048,   2048, 576);
    wtrans_k<<<dim3(48, 96),  tblk, 0, stream>>>(q_b_w,  qbwt,  1536, 3072);
    wtrans_k<<<dim3(16, 128), tblk, 0, stream>>>(kv_b_w, kvbwt, 512,  4096);
    wtrans_k<<<dim3(64, 64),  tblk, 0, stream>>>(o_w,    owt,   2048, 2048);

    // 1) [q_a | ckv] = x @ [q_a_w | kv_a_w]  (merged, N=2176)
    gemm_bt<0><<<dim3(17, 16), blk, 0, stream>>>(xb, W1, qkv_a, 2048, 2048, 2048, 2176);
    rmsnorm_k<<<dim3(2048), blk, 0, stream>>>(qkv_a, q_a_ln, 1536, 2176);
    kvcache_k<<<dim3(2048), blk, 0, stream>>>(qkv_a, kv_a_ln, posid, cosb, sinb, kv_out, cnb, kpe);

    // 2) q = q_a_norm @ q_b_w ; rope + relayout (+ exp2-domain pre-scale)
    gemm_bt<0><<<dim3(24, 16), blk, 0, stream>>>(qkv_a, qbwt, qbuf, 1536, 2176, 1536, 3072);
    qrope_k<<<dim3(2048), blk, 0, stream>>>(qbuf, posid, cosb, sinb, query);

    // 3) kv = c_norm @ kv_b_w ; transpose value
    gemm_bt<0><<<dim3(32, 16), blk, 0, stream>>>(cnb, kvbwt, kvbuf, 512, 512, 512, 4096);
    vtrans_k<<<dim3(64, 4, 16), tblk, 0, stream>>>(kvbuf, vt);

    // 4) fused flash attention (balanced 1D grid) -> ao bf16 [S][H*128]
    flash_attn<<<dim3(512), dim3(256), 0, stream>>>(query, kvbuf, kpe, vt, ao);

    // 5) out = ao @ o_w (fp32)
    gemm_bt<1><<<dim3(16, 16), blk, 0, stream>>>(ao, owt, out, 2048, 2048, 2048, 2048);
}

// Round 4
// 432.465 us; speedup vs baseline: 1.1511x; 1.0495x over previous
//
#include <hip/hip_runtime.h>

typedef unsigned short u16;
typedef __bf16 bf16x8 __attribute__((ext_vector_type(8)));
typedef short s16x4 __attribute__((ext_vector_type(4)));
typedef float f32x4 __attribute__((ext_vector_type(4)));

#define S_LEN 2048
#define NHEAD 16
#define QHEAD 192
#define EPS 1e-6f
#define ATTN_SCALE 0.07216878364870323f   /* 192^-0.5 */
#define QSCALE_LOG2E 0.10412011228586118f /* ATTN_SCALE * log2(e) */

__device__ __forceinline__ u16 f2bf(float f) {
    unsigned u = __builtin_bit_cast(unsigned, f);
    u = (u + 0x7FFFu + ((u >> 16) & 1u)) >> 16;
    return (u16)u;
}
__device__ __forceinline__ float bf2f(u16 h) {
    unsigned u = ((unsigned)h) << 16;
    return __builtin_bit_cast(float, u);
}

__device__ __forceinline__ void gl_lds16(const u16* g, u16* l) {
    __builtin_amdgcn_global_load_lds(
        (const __attribute__((address_space(1))) unsigned int*)g,
        (__attribute__((address_space(3))) unsigned int*)l,
        16, 0, 0);
}

#if defined(__has_builtin) && __has_builtin(__builtin_amdgcn_mfma_f32_16x16x16bf16_1k)
__device__ __forceinline__ f32x4 mfma16(s16x4 a, s16x4 b, f32x4 c) {
    return __builtin_amdgcn_mfma_f32_16x16x16bf16_1k(a, b, c, 0, 0, 0);
}
#else
__device__ __forceinline__ f32x4 mfma16(s16x4 a, s16x4 b, f32x4 c) {
    asm volatile("v_mfma_f32_16x16x16_bf16 %0, %1, %2, %0"
                 : "+v"(c) : "v"(a), "v"(b));
    return c;
}
#endif

// ---------------------------------------------------------------------------
// bf16 GEMM:  C[M][N] = A[M][K] @ Bt[N][K]^T   (unchanged)
// ---------------------------------------------------------------------------
template <int CF32>
__global__ __launch_bounds__(256, 2)
void gemm_bt(const u16* __restrict__ A, const u16* __restrict__ B,
             void* __restrict__ Cv, int K, int lda, int ldb, int ldc)
{
    const int tid = threadIdx.x;
    const int wave = tid >> 6, lane = tid & 63;
    const int q = lane >> 4, r = lane & 15;
    const int tm = blockIdx.y, tn = blockIdx.x;

    __shared__ __align__(16) u16 Al[128 * 32];
    __shared__ __align__(16) u16 Bl[128 * 32];

    const int lr = lane & 15;
    const int lc = (lane >> 4) * 8;
    const u16* ag0 = A + (long)(tm * 128 + wave * 32 + lr) * lda + lc;
    const u16* ag1 = ag0 + 16 * (long)lda;
    const u16* bg0 = B + (long)(tn * 128 + wave * 32 + lr) * ldb + lc;
    const u16* bg1 = bg0 + 16 * (long)ldb;
    u16* al0 = &Al[wave * 1024];
    u16* al1 = &Al[wave * 1024 + 512];
    u16* bl0 = &Bl[wave * 1024];
    u16* bl1 = &Bl[wave * 1024 + 512];

    f32x4 acc[4][4] = {};
    const int cm = (wave >> 1) * 4;
    const int cn = (wave & 1) * 4;

    for (int k0 = 0; k0 < K; k0 += 32) {
        gl_lds16(ag0 + k0, al0);
        gl_lds16(ag1 + k0, al1);
        gl_lds16(bg0 + k0, bl0);
        gl_lds16(bg1 + k0, bl1);
        __syncthreads();
        bf16x8 af[4], bv[4];
        #pragma unroll
        for (int mt = 0; mt < 4; ++mt) af[mt] = *(const bf16x8*)&Al[(cm + mt) * 512 + lane * 8];
        #pragma unroll
        for (int nt = 0; nt < 4; ++nt) bv[nt] = *(const bf16x8*)&Bl[(cn + nt) * 512 + lane * 8];
        #pragma unroll
        for (int mt = 0; mt < 4; ++mt)
            #pragma unroll
            for (int nt = 0; nt < 4; ++nt)
                acc[mt][nt] = __builtin_amdgcn_mfma_f32_16x16x32_bf16(
                    af[mt], bv[nt], acc[mt][nt], 0, 0, 0);
        __syncthreads();
    }

    const int wm = (wave >> 1) * 64, wn = (wave & 1) * 64;
    const int row0 = tm * 128 + wm + q * 4;
    const int col0 = tn * 128 + wn + r;
    if (CF32) {
        float* C = (float*)Cv;
        #pragma unroll
        for (int mt = 0; mt < 4; ++mt)
            #pragma unroll
            for (int i = 0; i < 4; ++i) {
                long rb = (long)(row0 + mt * 16 + i) * ldc + col0;
                #pragma unroll
                for (int nt = 0; nt < 4; ++nt)
                    C[rb + nt * 16] = acc[mt][nt][i];
            }
    } else {
        u16* C = (u16*)Cv;
        #pragma unroll
        for (int mt = 0; mt < 4; ++mt)
            #pragma unroll
            for (int i = 0; i < 4; ++i) {
                long rb = (long)(row0 + mt * 16 + i) * ldc + col0;
                #pragma unroll
                for (int nt = 0; nt < 4; ++nt)
                    C[rb + nt * 16] = f2bf(acc[mt][nt][i]);
            }
    }
}

// ---------------------------------------------------------------------------
// Flash attention, S^T formulation, double-buffered prefetch pipeline.
// Block = 256 threads (4 waves). q-tile 64: wave w owns q rows
// [q0+w*16, q0+w*16+16) exclusively (one 16-col n-block) -> no merge.
// kv-tile 64, processed one per iteration by ALL waves from one 40KB
// buffer while the NEXT tile is prefetched into the other buffer.
// Buffer selection is OFFSET ARITHMETIC on one smem base (a ternary
// select of LDS pointers into global_load_lds miscompiles on gfx950:
// "V_CMP_NE_U32_e32 0, $src_shared_base" backend error).
// LDS: 2 x 40KB = 80KB -> 2 blocks/CU -> 8 waves/CU.
// Maxless exp2-domain softmax (query pre-scaled by SCALE*log2e).
//
// Grid: 1D 512, complementary mapping (kept from round 2 - it cut
// FETCH_SIZE 4x): blocks [0,256) -> heavy strips j=31-t, [256,512) ->
// light strips j=t, h = i&15.
// ---------------------------------------------------------------------------
template<int C0, int C1>
__device__ __forceinline__ void stage_tile(
    const u16* __restrict__ kvb, const u16* __restrict__ kpe,
    const u16* __restrict__ vt,
    u16* __restrict__ Kl, u16* __restrict__ Vl,
    int h, int t, int quad, int r)
{
    #pragma unroll
    for (int c = C0; c < C1; ++c) {
        if (c < 24) {
            const int mtk = c / 6, kc = c % 6;
            const int row = t * 64 + mtk * 16 + r;
            const u16* src = (kc < 4)
                ? kvb + (size_t)row * 4096 + h * 256 + kc * 32 + quad * 8
                : kpe + (size_t)row * 64 + (kc - 4) * 32 + quad * 8;
            gl_lds16(src, &Kl[c * 512]);
        } else {
            const int cv = c - 24, mtd = cv >> 1, sc = cv & 1;
            const u16* src = vt + ((size_t)h * 128 + mtd * 16 + r) * 2048
                             + t * 64 + sc * 32 + quad * 8;
            gl_lds16(src, &Vl[cv * 512]);
        }
    }
}

__device__ __forceinline__ void stage_dispatch(
    const u16* __restrict__ kvb, const u16* __restrict__ kpe,
    const u16* __restrict__ vt,
    u16* __restrict__ Kl, u16* __restrict__ Vl,
    int w, int h, int t, int quad, int r)
{
    if (w == 0)      stage_tile<0, 10>(kvb, kpe, vt, Kl, Vl, h, t, quad, r);
    else if (w == 1) stage_tile<10, 20>(kvb, kpe, vt, Kl, Vl, h, t, quad, r);
    else if (w == 2) stage_tile<20, 30>(kvb, kpe, vt, Kl, Vl, h, t, quad, r);
    else             stage_tile<30, 40>(kvb, kpe, vt, Kl, Vl, h, t, quad, r);
}

__device__ __forceinline__ void kv_tile_step(
    const u16* __restrict__ Kl, const u16* __restrict__ Vl,
    const bf16x8 (&Qf)[6], f32x4 (&Oacc)[8], float& lsum,
    int lane, int quad, int r, int kglob0, int qg, bool maskT)
{
    f32x4 Sacc[4];
    #pragma unroll
    for (int mtk = 0; mtk < 4; ++mtk)
        Sacc[mtk] = (f32x4){0.f, 0.f, 0.f, 0.f};
    #pragma unroll
    for (int kc = 0; kc < 6; ++kc)
        #pragma unroll
        for (int mtk = 0; mtk < 4; ++mtk) {
            bf16x8 Ak = *(const bf16x8*)&Kl[(mtk * 6 + kc) * 512 + lane * 8];
            Sacc[mtk] = __builtin_amdgcn_mfma_f32_16x16x32_bf16(
                Ak, Qf[kc], Sacc[mtk], 0, 0, 0);
        }
    #pragma unroll
    for (int kb = 0; kb < 4; ++kb) {
        s16x4 Pf;
        const int kb0 = kglob0 + kb * 16 + quad * 4;
        #pragma unroll
        for (int i = 0; i < 4; ++i) {
            float p = exp2f(Sacc[kb][i]);
            if (maskT && (kb0 + i > qg)) p = 0.f;
            lsum += p;
            Pf[i] = (short)f2bf(p);
        }
        #pragma unroll
        for (int mtd = 0; mtd < 8; ++mtd) {
            s16x4 Av = *(const s16x4*)&Vl[(mtd * 2 + (kb >> 1)) * 512
                         + ((kb & 1) * 2 + (quad >> 1)) * 128 + r * 8 + (quad & 1) * 4];
            Oacc[mtd] = mfma16(Av, Pf, Oacc[mtd]);
        }
    }
}

__global__ __launch_bounds__(256, 2)
void flash_attn(const u16* __restrict__ query, const u16* __restrict__ kvb,
                const u16* __restrict__ kpe, const u16* __restrict__ vt,
                u16* __restrict__ ao)
{
    const int tid = threadIdx.x;
    const int w = tid >> 6, lane = tid & 63;
    const int quad = lane >> 4, r = lane & 15;

    // Complementary work pairing (see header comment).
    const int bid = (int)blockIdx.x;
    const int i = bid & 255;
    const int t_ = i >> 4;
    const int h = i & 15;
    const int j = (bid < 256) ? (31 - t_) : t_;

    const int q0 = j * 64;
    const int ntk = j + 1;          // 64-wide kv tiles up to the diagonal

    __shared__ __align__(16) u16 smem[40960];   // 80KB: two 40KB tile buffers
    // buffer b at smem + b*20480: K = [0,12288) u16, V = [12288,20480) u16

    const int qg = q0 + w * 16 + r;   // this wave's q row (causal bound)

    bf16x8 Qf[6];
    #pragma unroll
    for (int kc = 0; kc < 6; ++kc)
        Qf[kc] = *(const bf16x8*)(query
            + ((size_t)h * S_LEN + q0 + w * 16 + r) * QHEAD
            + kc * 32 + quad * 8);

    f32x4 Oacc[8];
    #pragma unroll
    for (int mtd = 0; mtd < 8; ++mtd)
        Oacc[mtd] = (f32x4){0.f, 0.f, 0.f, 0.f};
    float lsum = 0.f;

    // prologue: stage tile 0 into buffer 0
    stage_dispatch(kvb, kpe, vt, smem, smem + 12288, w, h, 0, quad, r);
    __syncthreads();

    for (int t = 0; t < ntk; ++t) {
        u16* const curb = smem + (t & 1) * 20480;          // offset arith,
        u16* const nxtb = smem + ((t + 1) & 1) * 20480;    // no ptr select
        if (t + 1 < ntk)   // prefetch next tile into the other buffer
            stage_dispatch(kvb, kpe, vt, nxtb, nxtb + 12288, w, h, t + 1, quad, r);
        kv_tile_step(curb, curb + 12288, Qf, Oacc, lsum,
                     lane, quad, r, t * 64, qg, t == ntk - 1);
        __syncthreads();   // drains prefetch vmcnt + syncs buffer swap
    }

    // epilogue: each wave owns its 16 q-rows; reduce lsum over quads only
    float l = lsum;
    l += __shfl_xor(l, 16, 64);
    l += __shfl_xor(l, 32, 64);
    const float inv = 1.0f / l;
    const int qrow = q0 + w * 16 + r;
    #pragma unroll
    for (int mtd = 0; mtd < 8; ++mtd) {
        ushort4 o;
        o.x = f2bf(Oacc[mtd][0] * inv);
        o.y = f2bf(Oacc[mtd][1] * inv);
        o.z = f2bf(Oacc[mtd][2] * inv);
        o.w = f2bf(Oacc[mtd][3] * inv);
        *(ushort4*)(ao + (size_t)qrow * 2048 + h * 128 + mtd * 16 + quad * 4) = o;
    }
}

// ---------------------------------------------------------------------------
__global__ __launch_bounds__(256)
void cvt_f32_bf16(const float4* __restrict__ in, ushort4* __restrict__ out, int n4)
{
    int i = blockIdx.x * 256 + threadIdx.x;
    if (i < n4) {
        float4 v = in[i];
        ushort4 o;
        o.x = f2bf(v.x); o.y = f2bf(v.y); o.z = f2bf(v.z); o.w = f2bf(v.w);
        out[i] = o;
    }
}

// in fp32 [K][N] -> out bf16 [Npad][K], rows >= N zero-filled.
__global__ __launch_bounds__(256)
void wtrans_k(const float* __restrict__ in, u16* __restrict__ out, int K, int N)
{
    __shared__ float tile[32][33];
    int k0 = blockIdx.x * 32, n0 = blockIdx.y * 32;
    int tx = threadIdx.x, ty = threadIdx.y;
    #pragma unroll
    for (int j = 0; j < 32; j += 8) {
        int n = n0 + tx;
        tile[ty + j][tx] = (n < N) ? in[(long)(k0 + ty + j) * N + n] : 0.0f;
    }
    __syncthreads();
    #pragma unroll
    for (int j = 0; j < 32; j += 8)
        out[(long)(n0 + ty + j) * K + k0 + tx] = f2bf(tile[tx][ty + j]);
}

// RMS norm in-place on first D cols of rows with stride ld.
__global__ __launch_bounds__(256)
void rmsnorm_k(u16* __restrict__ X, const float* __restrict__ w, int D, int ld)
{
    u16* row = X + (long)blockIdx.x * ld;
    const int tid = threadIdx.x;
    __shared__ float red[4];
    float sum = 0.f;
    for (int d = tid; d < D; d += 256) { float v = bf2f(row[d]); sum += v * v; }
    #pragma unroll
    for (int o = 32; o; o >>= 1) sum += __shfl_xor(sum, o, 64);
    if ((tid & 63) == 0) red[tid >> 6] = sum;
    __syncthreads();
    sum = red[0] + red[1] + red[2] + red[3];
    float scale = rsqrtf(sum / (float)D + EPS);
    for (int d = tid; d < D; d += 256)
        row[d] = f2bf(bf2f(row[d]) * scale * w[d]);
}

// qkv_a bf16 [S][2176] cols 1536.. = [c(512)|k_pe(64)] -> kv_cache fp32
// [S][576], c_norm bf16 [S][512], roped k_pe bf16 [S][64].
__global__ __launch_bounds__(256)
void kvcache_k(const u16* __restrict__ qkv, const float* __restrict__ ln,
               const int* __restrict__ pos_ids, const float* __restrict__ cosb,
               const float* __restrict__ sinb, float* __restrict__ kvout,
               u16* __restrict__ cnb, u16* __restrict__ kpe)
{
    const int s = blockIdx.x, tid = threadIdx.x;
    const u16* row = qkv + (long)s * 2176 + 1536;
    __shared__ float red[4];
    float sum = 0.f;
    for (int d = tid; d < 512; d += 256) { float v = bf2f(row[d]); sum += v * v; }
    #pragma unroll
    for (int o = 32; o; o >>= 1) sum += __shfl_xor(sum, o, 64);
    if ((tid & 63) == 0) red[tid >> 6] = sum;
    __syncthreads();
    sum = red[0] + red[1] + red[2] + red[3];
    float scale = rsqrtf(sum / 512.f + EPS);
    for (int d = tid; d < 512; d += 256) {
        float v = bf2f(row[d]) * scale * ln[d];
        kvout[(long)s * 576 + d] = v;
        cnb[(long)s * 512 + d] = f2bf(v);
    }
    if (tid < 32) {
        int p = pos_ids[s];
        float x0 = bf2f(row[512 + 2 * tid]);
        float x1 = bf2f(row[512 + 2 * tid + 1]);
        float c1 = cosb[p * 64 + tid], s1 = sinb[p * 64 + tid];
        float c2 = cosb[p * 64 + 32 + tid], s2 = sinb[p * 64 + 32 + tid];
        float lo = x0 * c1 - x1 * s1;
        float hi = x1 * c2 + x0 * s2;
        kvout[(long)s * 576 + 512 + tid] = lo;
        kvout[(long)s * 576 + 544 + tid] = hi;
        kpe[(long)s * 64 + tid] = f2bf(lo);
        kpe[(long)s * 64 + 32 + tid] = f2bf(hi);
    }
}

// q bf16 [S][3072] -> query bf16 [H][S][192], rope on last 64 dims,
// all values pre-scaled by SCALE*log2(e) for exp2-domain softmax.
__global__ __launch_bounds__(256)
void qrope_k(const u16* __restrict__ qb, const int* __restrict__ pos_ids,
             const float* __restrict__ cosb, const float* __restrict__ sinb,
             u16* __restrict__ query)
{
    const int s = blockIdx.x, tid = threadIdx.x;
    const u16* row = qb + (long)s * 3072;
    {   // nope part: 16 heads x 16 chunks of 8, scaled
        int h = tid >> 4, c = tid & 15;
        const u16* src = &row[h * QHEAD + c * 8];
        u16* dst = &query[((long)(h * S_LEN + s)) * QHEAD + c * 8];
        ushort4 a = *(const ushort4*)src;
        ushort4 b = *(const ushort4*)(src + 4);
        ushort4 oa, ob;
        oa.x = f2bf(bf2f(a.x) * QSCALE_LOG2E); oa.y = f2bf(bf2f(a.y) * QSCALE_LOG2E);
        oa.z = f2bf(bf2f(a.z) * QSCALE_LOG2E); oa.w = f2bf(bf2f(a.w) * QSCALE_LOG2E);
        ob.x = f2bf(bf2f(b.x) * QSCALE_LOG2E); ob.y = f2bf(bf2f(b.y) * QSCALE_LOG2E);
        ob.z = f2bf(bf2f(b.z) * QSCALE_LOG2E); ob.w = f2bf(bf2f(b.w) * QSCALE_LOG2E);
        *(ushort4*)dst = oa;
        *(ushort4*)(dst + 4) = ob;
    }
    int p = pos_ids[s];
    for (int idx = tid; idx < 512; idx += 256) {
        int h = idx >> 5, i = idx & 31;
        float x0 = bf2f(row[h * QHEAD + 128 + 2 * i]);
        float x1 = bf2f(row[h * QHEAD + 128 + 2 * i + 1]);
        float c1 = cosb[p * 64 + i], s1 = sinb[p * 64 + i];
        float c2 = cosb[p * 64 + 32 + i], s2 = sinb[p * 64 + 32 + i];
        u16* qr = query + ((long)(h * S_LEN + s)) * QHEAD;
        qr[128 + i] = f2bf((x0 * c1 - x1 * s1) * QSCALE_LOG2E);
        qr[160 + i] = f2bf((x1 * c2 + x0 * s2) * QSCALE_LOG2E);
    }
}

// kv bf16 [S][4096] value part -> vt bf16 [H*128][S] (transposed)
__global__ __launch_bounds__(256)
void vtrans_k(const u16* __restrict__ kv, u16* __restrict__ vt)
{
    __shared__ u16 tile[32][33];
    int s0 = blockIdx.x * 32, d0 = blockIdx.y * 32, h = blockIdx.z;
    int tx = threadIdx.x, ty = threadIdx.y;
    #pragma unroll
    for (int j = 0; j < 32; j += 8)
        tile[ty + j][tx] = kv[(long)(s0 + ty + j) * 4096 + h * 256 + 128 + d0 + tx];
    __syncthreads();
    #pragma unroll
    for (int j = 0; j < 32; j += 8)
        vt[(long)(h * 128 + d0 + ty + j) * S_LEN + s0 + tx] = tile[tx][ty + j];
}

// ---------------------------------------------------------------------------
extern "C" void kernel_launch(void* const* d_in, const int* in_sizes, int n_in,
                              void* d_out, int out_size, void* d_ws, size_t ws_size,
                              hipStream_t stream)
{
    const float* x      = (const float*)d_in[0];
    const int*   posid  = (const int*)d_in[2];
    const float* cosb   = (const float*)d_in[3];
    const float* sinb   = (const float*)d_in[4];
    const float* q_a_w  = (const float*)d_in[5];
    const float* q_a_ln = (const float*)d_in[6];
    const float* q_b_w  = (const float*)d_in[7];
    const float* kv_a_w = (const float*)d_in[8];
    const float* kv_a_ln= (const float*)d_in[9];
    const float* kv_b_w = (const float*)d_in[10];
    const float* o_w    = (const float*)d_in[11];

    float* out    = (float*)d_out;
    float* kv_out = out + (size_t)2048 * 2048;

    char* ws = (char*)d_ws;
    size_t off = 0;
    auto alloc = [&](size_t bytes) { char* p = ws + off; off += (bytes + 255) & ~(size_t)255; return p; };
    u16* xb    = (u16*)alloc(2048ULL * 2048 * 2);
    u16* W1    = (u16*)alloc(2176ULL * 2048 * 2);   // [q_a^T ; kv_a^T(pad 640)]
    u16* qbwt  = (u16*)alloc(3072ULL * 1536 * 2);
    u16* kvbwt = (u16*)alloc(4096ULL * 512 * 2);
    u16* owt   = (u16*)alloc(2048ULL * 2048 * 2);
    u16* qkv_a = (u16*)alloc(2048ULL * 2176 * 2);   // [q_a(1536) | ckv(640)]
    u16* qbuf  = (u16*)alloc(2048ULL * 3072 * 2);
    u16* query = (u16*)alloc(16ULL * 2048 * 192 * 2);
    u16* cnb   = (u16*)alloc(2048ULL * 512 * 2);
    u16* kpe   = (u16*)alloc(2048ULL * 64 * 2);
    u16* kvbuf = (u16*)alloc(2048ULL * 4096 * 2);
    u16* vt    = (u16*)alloc(16ULL * 128 * 2048 * 2);
    u16* ao    = (u16*)alloc(2048ULL * 2048 * 2);
    (void)ws_size; (void)in_sizes; (void)n_in; (void)out_size;

    dim3 blk(256);
    dim3 tblk(32, 8);

    // 0) conversions / weight transposes
    cvt_f32_bf16<<<dim3(4096), blk, 0, stream>>>((const float4*)x, (ushort4*)xb, 2048 * 2048 / 4);
    wtrans_k<<<dim3(64, 48),  tblk, 0, stream>>>(q_a_w,  W1,                    2048, 1536);
    wtrans_k<<<dim3(64, 20),  tblk, 0, stream>>>(kv_a_w, W1 + 1536ULL * 2048,   2048, 576);
    wtrans_k<<<dim3(48, 96),  tblk, 0, stream>>>(q_b_w,  qbwt,  1536, 3072);
    wtrans_k<<<dim3(16, 128), tblk, 0, stream>>>(kv_b_w, kvbwt, 512,  4096);
    wtrans_k<<<dim3(64, 64),  tblk, 0, stream>>>(o_w,    owt,   2048, 2048);

    // 1) [q_a | ckv] = x @ [q_a_w | kv_a_w]  (merged, N=2176)
    gemm_bt<0><<<dim3(17, 16), blk, 0, stream>>>(xb, W1, qkv_a, 2048, 2048, 2048, 2176);
    rmsnorm_k<<<dim3(2048), blk, 0, stream>>>(qkv_a, q_a_ln, 1536, 2176);
    kvcache_k<<<dim3(2048), blk, 0, stream>>>(qkv_a, kv_a_ln, posid, cosb, sinb, kv_out, cnb, kpe);

    // 2) q = q_a_norm @ q_b_w ; rope + relayout (+ exp2-domain pre-scale)
    gemm_bt<0><<<dim3(24, 16), blk, 0, stream>>>(qkv_a, qbwt, qbuf, 1536, 2176, 1536, 3072);
    qrope_k<<<dim3(2048), blk, 0, stream>>>(qbuf, posid, cosb, sinb, query);

    // 3) kv = c_norm @ kv_b_w ; transpose value
    gemm_bt<0><<<dim3(32, 16), blk, 0, stream>>>(cnb, kvbwt, kvbuf, 512, 512, 512, 4096);
    vtrans_k<<<dim3(64, 4, 16), tblk, 0, stream>>>(kvbuf, vt);

    // 4) fused flash attention (pipelined double-buffer) -> ao bf16 [S][H*128]
    flash_attn<<<dim3(512), dim3(256), 0, stream>>>(query, kvbuf, kpe, vt, ao);

    // 5) out = ao @ o_w (fp32)
    gemm_bt<1><<<dim3(16, 16), blk, 0, stream>>>(ao, owt, out, 2048, 2048, 2048, 2048);
}

// Round 5
// 418.016 us; speedup vs baseline: 1.1909x; 1.0346x over previous
//
#include <hip/hip_runtime.h>

typedef unsigned short u16;
typedef __bf16 bf16x8 __attribute__((ext_vector_type(8)));
typedef short s16x4 __attribute__((ext_vector_type(4)));
typedef short s16x8 __attribute__((ext_vector_type(8)));
typedef float f32x4 __attribute__((ext_vector_type(4)));

#define S_LEN 2048
#define NHEAD 16
#define QHEAD 192
#define EPS 1e-6f
#define ATTN_SCALE 0.07216878364870323f   /* 192^-0.5 */
#define QSCALE_LOG2E 0.10412011228586118f /* ATTN_SCALE * log2(e) */

__device__ __forceinline__ u16 f2bf(float f) {
    unsigned u = __builtin_bit_cast(unsigned, f);
    u = (u + 0x7FFFu + ((u >> 16) & 1u)) >> 16;
    return (u16)u;
}
__device__ __forceinline__ float bf2f(u16 h) {
    unsigned u = ((unsigned)h) << 16;
    return __builtin_bit_cast(float, u);
}

__device__ __forceinline__ void gl_lds16(const u16* g, u16* l) {
    __builtin_amdgcn_global_load_lds(
        (const __attribute__((address_space(1))) unsigned int*)g,
        (__attribute__((address_space(3))) unsigned int*)l,
        16, 0, 0);
}

#if defined(__has_builtin) && __has_builtin(__builtin_amdgcn_mfma_f32_16x16x16bf16_1k)
__device__ __forceinline__ f32x4 mfma16(s16x4 a, s16x4 b, f32x4 c) {
    return __builtin_amdgcn_mfma_f32_16x16x16bf16_1k(a, b, c, 0, 0, 0);
}
#else
__device__ __forceinline__ f32x4 mfma16(s16x4 a, s16x4 b, f32x4 c) {
    asm volatile("v_mfma_f32_16x16x16_bf16 %0, %1, %2, %0"
                 : "+v"(c) : "v"(a), "v"(b));
    return c;
}
#endif

// ---------------------------------------------------------------------------
// bf16 GEMM:  C[M][N] = A[M][K] @ Bt[N][K]^T
// Single-barrier double-buffered pipeline (mirror of the flash_attn round-4
// win): prefetch K-step k+32 into buf^1 before computing from buf, one
// __syncthreads per iteration (its vmcnt drain overlaps the MFMAs).
// Buffer select is offset arithmetic (gfx950 addrspace-select miscompile).
// LDS 2 x 16KB = 32KB.
// ---------------------------------------------------------------------------
template <int CF32>
__global__ __launch_bounds__(256, 2)
void gemm_bt(const u16* __restrict__ A, const u16* __restrict__ B,
             void* __restrict__ Cv, int K, int lda, int ldb, int ldc)
{
    const int tid = threadIdx.x;
    const int wave = tid >> 6, lane = tid & 63;
    const int q = lane >> 4, r = lane & 15;
    const int tm = blockIdx.y, tn = blockIdx.x;

    __shared__ __align__(16) u16 smem[2 * 16384];   // buf b: A at b*16384, B at +8192

    const int lr = lane & 15;
    const int lc = (lane >> 4) * 8;
    const u16* ag0 = A + (long)(tm * 128 + wave * 32 + lr) * lda + lc;
    const u16* ag1 = ag0 + 16 * (long)lda;
    const u16* bg0 = B + (long)(tn * 128 + wave * 32 + lr) * ldb + lc;
    const u16* bg1 = bg0 + 16 * (long)ldb;
    const int sa0 = wave * 1024;
    const int sa1 = wave * 1024 + 512;
    const int sb0 = 8192 + wave * 1024;
    const int sb1 = 8192 + wave * 1024 + 512;

    f32x4 acc[4][4] = {};
    const int cm = (wave >> 1) * 4;
    const int cn = (wave & 1) * 4;

    // prologue: stage k0=0 into buffer 0
    gl_lds16(ag0, smem + sa0);
    gl_lds16(ag1, smem + sa1);
    gl_lds16(bg0, smem + sb0);
    gl_lds16(bg1, smem + sb1);
    __syncthreads();

    int p = 0;
    for (int k0 = 0; k0 < K; k0 += 32) {
        u16* const cur = smem + p * 16384;
        u16* const nxt = smem + (p ^ 1) * 16384;
        if (k0 + 32 < K) {      // prefetch next K-step
            gl_lds16(ag0 + k0 + 32, nxt + sa0);
            gl_lds16(ag1 + k0 + 32, nxt + sa1);
            gl_lds16(bg0 + k0 + 32, nxt + sb0);
            gl_lds16(bg1 + k0 + 32, nxt + sb1);
        }
        bf16x8 af[4], bv[4];
        #pragma unroll
        for (int mt = 0; mt < 4; ++mt) af[mt] = *(const bf16x8*)&cur[(cm + mt) * 512 + lane * 8];
        #pragma unroll
        for (int nt = 0; nt < 4; ++nt) bv[nt] = *(const bf16x8*)&cur[8192 + (cn + nt) * 512 + lane * 8];
        #pragma unroll
        for (int mt = 0; mt < 4; ++mt)
            #pragma unroll
            for (int nt = 0; nt < 4; ++nt)
                acc[mt][nt] = __builtin_amdgcn_mfma_f32_16x16x32_bf16(
                    af[mt], bv[nt], acc[mt][nt], 0, 0, 0);
        __syncthreads();   // drains prefetch + buffer swap
        p ^= 1;
    }

    const int wm = (wave >> 1) * 64, wn = (wave & 1) * 64;
    const int row0 = tm * 128 + wm + q * 4;
    const int col0 = tn * 128 + wn + r;
    if (CF32) {
        float* C = (float*)Cv;
        #pragma unroll
        for (int mt = 0; mt < 4; ++mt)
            #pragma unroll
            for (int i = 0; i < 4; ++i) {
                long rb = (long)(row0 + mt * 16 + i) * ldc + col0;
                #pragma unroll
                for (int nt = 0; nt < 4; ++nt)
                    C[rb + nt * 16] = acc[mt][nt][i];
            }
    } else {
        u16* C = (u16*)Cv;
        #pragma unroll
        for (int mt = 0; mt < 4; ++mt)
            #pragma unroll
            for (int i = 0; i < 4; ++i) {
                long rb = (long)(row0 + mt * 16 + i) * ldc + col0;
                #pragma unroll
                for (int nt = 0; nt < 4; ++nt)
                    C[rb + nt * 16] = f2bf(acc[mt][nt][i]);
            }
    }
}

// ---------------------------------------------------------------------------
// Flash attention, S^T formulation, double-buffered prefetch pipeline.
// Block = 256 threads (4 waves). q-tile 64: wave w owns q rows
// [q0+w*16, q0+w*16+16). kv-tile 64, one per iteration, all waves.
// LDS: 2 x 40KB = 80KB -> 2 blocks/CU -> 8 waves/CU.
// Maxless exp2-domain softmax (query pre-scaled by SCALE*log2e).
//
// PV reads are ds_read_b128 pairs (conflict-free, 1KB wave span): vt's
// s-axis is PERMUTED within each 32-block (by vtrans_k's write) so one
// 16B lane read holds the A-fragments for kb and kb+1:
//   permuted position quad*8 + half*4 + i  <->  s = half*16 + quad*4 + i.
// The old b64 pattern spanned 512B -> 4-way bank conflict (4.33M cycles
// in round 4's counters).
// ---------------------------------------------------------------------------
template<int C0, int C1>
__device__ __forceinline__ void stage_tile(
    const u16* __restrict__ kvb, const u16* __restrict__ kpe,
    const u16* __restrict__ vt,
    u16* __restrict__ Kl, u16* __restrict__ Vl,
    int h, int t, int quad, int r)
{
    #pragma unroll
    for (int c = C0; c < C1; ++c) {
        if (c < 24) {
            const int mtk = c / 6, kc = c % 6;
            const int row = t * 64 + mtk * 16 + r;
            const u16* src = (kc < 4)
                ? kvb + (size_t)row * 4096 + h * 256 + kc * 32 + quad * 8
                : kpe + (size_t)row * 64 + (kc - 4) * 32 + quad * 8;
            gl_lds16(src, &Kl[c * 512]);
        } else {
            const int cv = c - 24, mtd = cv >> 1, sc = cv & 1;
            const u16* src = vt + ((size_t)h * 128 + mtd * 16 + r) * 2048
                             + t * 64 + sc * 32 + quad * 8;
            gl_lds16(src, &Vl[cv * 512]);
        }
    }
}

__device__ __forceinline__ void stage_dispatch(
    const u16* __restrict__ kvb, const u16* __restrict__ kpe,
    const u16* __restrict__ vt,
    u16* __restrict__ Kl, u16* __restrict__ Vl,
    int w, int h, int t, int quad, int r)
{
    if (w == 0)      stage_tile<0, 10>(kvb, kpe, vt, Kl, Vl, h, t, quad, r);
    else if (w == 1) stage_tile<10, 20>(kvb, kpe, vt, Kl, Vl, h, t, quad, r);
    else if (w == 2) stage_tile<20, 30>(kvb, kpe, vt, Kl, Vl, h, t, quad, r);
    else             stage_tile<30, 40>(kvb, kpe, vt, Kl, Vl, h, t, quad, r);
}

__device__ __forceinline__ void kv_tile_step(
    const u16* __restrict__ Kl, const u16* __restrict__ Vl,
    const bf16x8 (&Qf)[6], f32x4 (&Oacc)[8], float& lsum,
    int lane, int quad, int r, int kglob0, int qg, bool maskT)
{
    f32x4 Sacc[4];
    #pragma unroll
    for (int mtk = 0; mtk < 4; ++mtk)
        Sacc[mtk] = (f32x4){0.f, 0.f, 0.f, 0.f};
    #pragma unroll
    for (int kc = 0; kc < 6; ++kc)
        #pragma unroll
        for (int mtk = 0; mtk < 4; ++mtk) {
            bf16x8 Ak = *(const bf16x8*)&Kl[(mtk * 6 + kc) * 512 + lane * 8];
            Sacc[mtk] = __builtin_amdgcn_mfma_f32_16x16x32_bf16(
                Ak, Qf[kc], Sacc[mtk], 0, 0, 0);
        }
    #pragma unroll
    for (int sc = 0; sc < 2; ++sc) {
        s16x4 Pf[2];
        #pragma unroll
        for (int half = 0; half < 2; ++half) {
            const int kb = sc * 2 + half;
            const int kb0 = kglob0 + kb * 16 + quad * 4;
            #pragma unroll
            for (int i = 0; i < 4; ++i) {
                float pv = exp2f(Sacc[kb][i]);
                if (maskT && (kb0 + i > qg)) pv = 0.f;
                lsum += pv;
                Pf[half][i] = (short)f2bf(pv);
            }
        }
        #pragma unroll
        for (int mtd = 0; mtd < 8; ++mtd) {
            s16x8 Av8 = *(const s16x8*)&Vl[(mtd * 2 + sc) * 512 + quad * 128 + r * 8];
            s16x4 lo = __builtin_shufflevector(Av8, Av8, 0, 1, 2, 3);
            s16x4 hi = __builtin_shufflevector(Av8, Av8, 4, 5, 6, 7);
            Oacc[mtd] = mfma16(lo, Pf[0], Oacc[mtd]);
            Oacc[mtd] = mfma16(hi, Pf[1], Oacc[mtd]);
        }
    }
}

__global__ __launch_bounds__(256, 2)
void flash_attn(const u16* __restrict__ query, const u16* __restrict__ kvb,
                const u16* __restrict__ kpe, const u16* __restrict__ vt,
                u16* __restrict__ ao)
{
    const int tid = threadIdx.x;
    const int w = tid >> 6, lane = tid & 63;
    const int quad = lane >> 4, r = lane & 15;

    // Complementary work pairing (blocks b and b+256 share a CU).
    const int bid = (int)blockIdx.x;
    const int i = bid & 255;
    const int t_ = i >> 4;
    const int h = i & 15;
    const int j = (bid < 256) ? (31 - t_) : t_;

    const int q0 = j * 64;
    const int ntk = j + 1;          // 64-wide kv tiles up to the diagonal

    __shared__ __align__(16) u16 smem[40960];   // 80KB: two 40KB tile buffers
    // buffer b at smem + b*20480: K = [0,12288) u16, V = [12288,20480) u16

    const int qg = q0 + w * 16 + r;   // this wave's q row (causal bound)

    bf16x8 Qf[6];
    #pragma unroll
    for (int kc = 0; kc < 6; ++kc)
        Qf[kc] = *(const bf16x8*)(query
            + ((size_t)h * S_LEN + q0 + w * 16 + r) * QHEAD
            + kc * 32 + quad * 8);

    f32x4 Oacc[8];
    #pragma unroll
    for (int mtd = 0; mtd < 8; ++mtd)
        Oacc[mtd] = (f32x4){0.f, 0.f, 0.f, 0.f};
    float lsum = 0.f;

    // prologue: stage tile 0 into buffer 0
    stage_dispatch(kvb, kpe, vt, smem, smem + 12288, w, h, 0, quad, r);
    __syncthreads();

    for (int t = 0; t < ntk; ++t) {
        u16* const curb = smem + (t & 1) * 20480;          // offset arith,
        u16* const nxtb = smem + ((t + 1) & 1) * 20480;    // no ptr select
        if (t + 1 < ntk)   // prefetch next tile into the other buffer
            stage_dispatch(kvb, kpe, vt, nxtb, nxtb + 12288, w, h, t + 1, quad, r);
        kv_tile_step(curb, curb + 12288, Qf, Oacc, lsum,
                     lane, quad, r, t * 64, qg, t == ntk - 1);
        __syncthreads();   // drains prefetch vmcnt + syncs buffer swap
    }

    // epilogue: each wave owns its 16 q-rows; reduce lsum over quads only
    float l = lsum;
    l += __shfl_xor(l, 16, 64);
    l += __shfl_xor(l, 32, 64);
    const float inv = 1.0f / l;
    const int qrow = q0 + w * 16 + r;
    #pragma unroll
    for (int mtd = 0; mtd < 8; ++mtd) {
        ushort4 o;
        o.x = f2bf(Oacc[mtd][0] * inv);
        o.y = f2bf(Oacc[mtd][1] * inv);
        o.z = f2bf(Oacc[mtd][2] * inv);
        o.w = f2bf(Oacc[mtd][3] * inv);
        *(ushort4*)(ao + (size_t)qrow * 2048 + h * 128 + mtd * 16 + quad * 4) = o;
    }
}

// ---------------------------------------------------------------------------
__global__ __launch_bounds__(256)
void cvt_f32_bf16(const float4* __restrict__ in, ushort4* __restrict__ out, int n4)
{
    int i = blockIdx.x * 256 + threadIdx.x;
    if (i < n4) {
        float4 v = in[i];
        ushort4 o;
        o.x = f2bf(v.x); o.y = f2bf(v.y); o.z = f2bf(v.z); o.w = f2bf(v.w);
        out[i] = o;
    }
}

// in fp32 [K][N] -> out bf16 [Npad][K], rows >= N zero-filled.
__global__ __launch_bounds__(256)
void wtrans_k(const float* __restrict__ in, u16* __restrict__ out, int K, int N)
{
    __shared__ float tile[32][33];
    int k0 = blockIdx.x * 32, n0 = blockIdx.y * 32;
    int tx = threadIdx.x, ty = threadIdx.y;
    #pragma unroll
    for (int j = 0; j < 32; j += 8) {
        int n = n0 + tx;
        tile[ty + j][tx] = (n < N) ? in[(long)(k0 + ty + j) * N + n] : 0.0f;
    }
    __syncthreads();
    #pragma unroll
    for (int j = 0; j < 32; j += 8)
        out[(long)(n0 + ty + j) * K + k0 + tx] = f2bf(tile[tx][ty + j]);
}

// RMS norm in-place on first D cols of rows with stride ld.
__global__ __launch_bounds__(256)
void rmsnorm_k(u16* __restrict__ X, const float* __restrict__ w, int D, int ld)
{
    u16* row = X + (long)blockIdx.x * ld;
    const int tid = threadIdx.x;
    __shared__ float red[4];
    float sum = 0.f;
    for (int d = tid; d < D; d += 256) { float v = bf2f(row[d]); sum += v * v; }
    #pragma unroll
    for (int o = 32; o; o >>= 1) sum += __shfl_xor(sum, o, 64);
    if ((tid & 63) == 0) red[tid >> 6] = sum;
    __syncthreads();
    sum = red[0] + red[1] + red[2] + red[3];
    float scale = rsqrtf(sum / (float)D + EPS);
    for (int d = tid; d < D; d += 256)
        row[d] = f2bf(bf2f(row[d]) * scale * w[d]);
}

// qkv_a bf16 [S][2176] cols 1536.. = [c(512)|k_pe(64)] -> kv_cache fp32
// [S][576], c_norm bf16 [S][512], roped k_pe bf16 [S][64].
__global__ __launch_bounds__(256)
void kvcache_k(const u16* __restrict__ qkv, const float* __restrict__ ln,
               const int* __restrict__ pos_ids, const float* __restrict__ cosb,
               const float* __restrict__ sinb, float* __restrict__ kvout,
               u16* __restrict__ cnb, u16* __restrict__ kpe)
{
    const int s = blockIdx.x, tid = threadIdx.x;
    const u16* row = qkv + (long)s * 2176 + 1536;
    __shared__ float red[4];
    float sum = 0.f;
    for (int d = tid; d < 512; d += 256) { float v = bf2f(row[d]); sum += v * v; }
    #pragma unroll
    for (int o = 32; o; o >>= 1) sum += __shfl_xor(sum, o, 64);
    if ((tid & 63) == 0) red[tid >> 6] = sum;
    __syncthreads();
    sum = red[0] + red[1] + red[2] + red[3];
    float scale = rsqrtf(sum / 512.f + EPS);
    for (int d = tid; d < 512; d += 256) {
        float v = bf2f(row[d]) * scale * ln[d];
        kvout[(long)s * 576 + d] = v;
        cnb[(long)s * 512 + d] = f2bf(v);
    }
    if (tid < 32) {
        int p = pos_ids[s];
        float x0 = bf2f(row[512 + 2 * tid]);
        float x1 = bf2f(row[512 + 2 * tid + 1]);
        float c1 = cosb[p * 64 + tid], s1 = sinb[p * 64 + tid];
        float c2 = cosb[p * 64 + 32 + tid], s2 = sinb[p * 64 + 32 + tid];
        float lo = x0 * c1 - x1 * s1;
        float hi = x1 * c2 + x0 * s2;
        kvout[(long)s * 576 + 512 + tid] = lo;
        kvout[(long)s * 576 + 544 + tid] = hi;
        kpe[(long)s * 64 + tid] = f2bf(lo);
        kpe[(long)s * 64 + 32 + tid] = f2bf(hi);
    }
}

// q bf16 [S][3072] -> query bf16 [H][S][192], rope on last 64 dims,
// all values pre-scaled by SCALE*log2(e) for exp2-domain softmax.
__global__ __launch_bounds__(256)
void qrope_k(const u16* __restrict__ qb, const int* __restrict__ pos_ids,
             const float* __restrict__ cosb, const float* __restrict__ sinb,
             u16* __restrict__ query)
{
    const int s = blockIdx.x, tid = threadIdx.x;
    const u16* row = qb + (long)s * 3072;
    {   // nope part: 16 heads x 16 chunks of 8, scaled
        int h = tid >> 4, c = tid & 15;
        const u16* src = &row[h * QHEAD + c * 8];
        u16* dst = &query[((long)(h * S_LEN + s)) * QHEAD + c * 8];
        ushort4 a = *(const ushort4*)src;
        ushort4 b = *(const ushort4*)(src + 4);
        ushort4 oa, ob;
        oa.x = f2bf(bf2f(a.x) * QSCALE_LOG2E); oa.y = f2bf(bf2f(a.y) * QSCALE_LOG2E);
        oa.z = f2bf(bf2f(a.z) * QSCALE_LOG2E); oa.w = f2bf(bf2f(a.w) * QSCALE_LOG2E);
        ob.x = f2bf(bf2f(b.x) * QSCALE_LOG2E); ob.y = f2bf(bf2f(b.y) * QSCALE_LOG2E);
        ob.z = f2bf(bf2f(b.z) * QSCALE_LOG2E); ob.w = f2bf(bf2f(b.w) * QSCALE_LOG2E);
        *(ushort4*)dst = oa;
        *(ushort4*)(dst + 4) = ob;
    }
    int p = pos_ids[s];
    for (int idx = tid; idx < 512; idx += 256) {
        int h = idx >> 5, i = idx & 31;
        float x0 = bf2f(row[h * QHEAD + 128 + 2 * i]);
        float x1 = bf2f(row[h * QHEAD + 128 + 2 * i + 1]);
        float c1 = cosb[p * 64 + i], s1 = sinb[p * 64 + i];
        float c2 = cosb[p * 64 + 32 + i], s2 = sinb[p * 64 + 32 + i];
        u16* qr = query + ((long)(h * S_LEN + s)) * QHEAD;
        qr[128 + i] = f2bf((x0 * c1 - x1 * s1) * QSCALE_LOG2E);
        qr[160 + i] = f2bf((x1 * c2 + x0 * s2) * QSCALE_LOG2E);
    }
}

// kv bf16 [S][4096] value part -> vt bf16 [H*128][S] (transposed).
// The s-axis is permuted within each 32-block so flash PV can read b128:
// new position quad*8 + half*4 + i  <-> old s = half*16 + quad*4 + i.
__global__ __launch_bounds__(256)
void vtrans_k(const u16* __restrict__ kv, u16* __restrict__ vt)
{
    __shared__ u16 tile[32][33];
    int s0 = blockIdx.x * 32, d0 = blockIdx.y * 32, h = blockIdx.z;
    int tx = threadIdx.x, ty = threadIdx.y;
    #pragma unroll
    for (int j = 0; j < 32; j += 8)
        tile[ty + j][tx] = kv[(long)(s0 + ty + j) * 4096 + h * 256 + 128 + d0 + tx];
    __syncthreads();
    const int txp = ((tx >> 2) & 3) * 8 + (tx >> 4) * 4 + (tx & 3);
    #pragma unroll
    for (int j = 0; j < 32; j += 8)
        vt[(long)(h * 128 + d0 + ty + j) * S_LEN + s0 + txp] = tile[tx][ty + j];
}

// ---------------------------------------------------------------------------
extern "C" void kernel_launch(void* const* d_in, const int* in_sizes, int n_in,
                              void* d_out, int out_size, void* d_ws, size_t ws_size,
                              hipStream_t stream)
{
    const float* x      = (const float*)d_in[0];
    const int*   posid  = (const int*)d_in[2];
    const float* cosb   = (const float*)d_in[3];
    const float* sinb   = (const float*)d_in[4];
    const float* q_a_w  = (const float*)d_in[5];
    const float* q_a_ln = (const float*)d_in[6];
    const float* q_b_w  = (const float*)d_in[7];
    const float* kv_a_w = (const float*)d_in[8];
    const float* kv_a_ln= (const float*)d_in[9];
    const float* kv_b_w = (const float*)d_in[10];
    const float* o_w    = (const float*)d_in[11];

    float* out    = (float*)d_out;
    float* kv_out = out + (size_t)2048 * 2048;

    char* ws = (char*)d_ws;
    size_t off = 0;
    auto alloc = [&](size_t bytes) { char* p = ws + off; off += (bytes + 255) & ~(size_t)255; return p; };
    u16* xb    = (u16*)alloc(2048ULL * 2048 * 2);
    u16* W1    = (u16*)alloc(2176ULL * 2048 * 2);   // [q_a^T ; kv_a^T(pad 640)]
    u16* qbwt  = (u16*)alloc(3072ULL * 1536 * 2);
    u16* kvbwt = (u16*)alloc(4096ULL * 512 * 2);
    u16* owt   = (u16*)alloc(2048ULL * 2048 * 2);
    u16* qkv_a = (u16*)alloc(2048ULL * 2176 * 2);   // [q_a(1536) | ckv(640)]
    u16* qbuf  = (u16*)alloc(2048ULL * 3072 * 2);
    u16* query = (u16*)alloc(16ULL * 2048 * 192 * 2);
    u16* cnb   = (u16*)alloc(2048ULL * 512 * 2);
    u16* kpe   = (u16*)alloc(2048ULL * 64 * 2);
    u16* kvbuf = (u16*)alloc(2048ULL * 4096 * 2);
    u16* vt    = (u16*)alloc(16ULL * 128 * 2048 * 2);
    u16* ao    = (u16*)alloc(2048ULL * 2048 * 2);
    (void)ws_size; (void)in_sizes; (void)n_in; (void)out_size;

    dim3 blk(256);
    dim3 tblk(32, 8);

    // 0) conversions / weight transposes
    cvt_f32_bf16<<<dim3(4096), blk, 0, stream>>>((const float4*)x, (ushort4*)xb, 2048 * 2048 / 4);
    wtrans_k<<<dim3(64, 48),  tblk, 0, stream>>>(q_a_w,  W1,                    2048, 1536);
    wtrans_k<<<dim3(64, 20),  tblk, 0, stream>>>(kv_a_w, W1 + 1536ULL * 2048,   2048, 576);
    wtrans_k<<<dim3(48, 96),  tblk, 0, stream>>>(q_b_w,  qbwt,  1536, 3072);
    wtrans_k<<<dim3(16, 128), tblk, 0, stream>>>(kv_b_w, kvbwt, 512,  4096);
    wtrans_k<<<dim3(64, 64),  tblk, 0, stream>>>(o_w,    owt,   2048, 2048);

    // 1) [q_a | ckv] = x @ [q_a_w | kv_a_w]  (merged, N=2176)
    gemm_bt<0><<<dim3(17, 16), blk, 0, stream>>>(xb, W1, qkv_a, 2048, 2048, 2048, 2176);
    rmsnorm_k<<<dim3(2048), blk, 0, stream>>>(qkv_a, q_a_ln, 1536, 2176);
    kvcache_k<<<dim3(2048), blk, 0, stream>>>(qkv_a, kv_a_ln, posid, cosb, sinb, kv_out, cnb, kpe);

    // 2) q = q_a_norm @ q_b_w ; rope + relayout (+ exp2-domain pre-scale)
    gemm_bt<0><<<dim3(24, 16), blk, 0, stream>>>(qkv_a, qbwt, qbuf, 1536, 2176, 1536, 3072);
    qrope_k<<<dim3(2048), blk, 0, stream>>>(qbuf, posid, cosb, sinb, query);

    // 3) kv = c_norm @ kv_b_w ; transpose value (s-permuted for PV b128)
    gemm_bt<0><<<dim3(32, 16), blk, 0, stream>>>(cnb, kvbwt, kvbuf, 512, 512, 512, 4096);
    vtrans_k<<<dim3(64, 4, 16), tblk, 0, stream>>>(kvbuf, vt);

    // 4) fused flash attention (pipelined double-buffer) -> ao bf16 [S][H*128]
    flash_attn<<<dim3(512), dim3(256), 0, stream>>>(query, kvbuf, kpe, vt, ao);

    // 5) out = ao @ o_w (fp32)
    gemm_bt<1><<<dim3(16, 16), blk, 0, stream>>>(ao, owt, out, 2048, 2048, 2048, 2048);
}

// Round 6
// 417.401 us; speedup vs baseline: 1.1926x; 1.0015x over previous
//
#include <hip/hip_runtime.h>

typedef unsigned short u16;
typedef __bf16 bf16x8 __attribute__((ext_vector_type(8)));
typedef short s16x4 __attribute__((ext_vector_type(4)));
typedef short s16x8 __attribute__((ext_vector_type(8)));
typedef float f32x4 __attribute__((ext_vector_type(4)));

#define S_LEN 2048
#define NHEAD 16
#define QHEAD 192
#define EPS 1e-6f
#define ATTN_SCALE 0.07216878364870323f   /* 192^-0.5 */
#define QSCALE_LOG2E 0.10412011228586118f /* ATTN_SCALE * log2(e) */

__device__ __forceinline__ u16 f2bf(float f) {
    unsigned u = __builtin_bit_cast(unsigned, f);
    u = (u + 0x7FFFu + ((u >> 16) & 1u)) >> 16;
    return (u16)u;
}
__device__ __forceinline__ float bf2f(u16 h) {
    unsigned u = ((unsigned)h) << 16;
    return __builtin_bit_cast(float, u);
}

__device__ __forceinline__ void gl_lds16(const u16* g, u16* l) {
    __builtin_amdgcn_global_load_lds(
        (const __attribute__((address_space(1))) unsigned int*)g,
        (__attribute__((address_space(3))) unsigned int*)l,
        16, 0, 0);
}

#if defined(__has_builtin) && __has_builtin(__builtin_amdgcn_mfma_f32_16x16x16bf16_1k)
__device__ __forceinline__ f32x4 mfma16(s16x4 a, s16x4 b, f32x4 c) {
    return __builtin_amdgcn_mfma_f32_16x16x16bf16_1k(a, b, c, 0, 0, 0);
}
#else
__device__ __forceinline__ f32x4 mfma16(s16x4 a, s16x4 b, f32x4 c) {
    asm volatile("v_mfma_f32_16x16x16_bf16 %0, %1, %2, %0"
                 : "+v"(c) : "v"(a), "v"(b));
    return c;
}
#endif

// ---------------------------------------------------------------------------
// bf16 GEMM:  C[M][N] = A[M][K] @ Bt[N][K]^T
// 8-wave (512-thread) blocks, 128x128 tile, single-barrier double-buffered
// prefetch pipeline. Round-5 post-mortem: at 4-wave blocks and grids of
// 256-384 (1-1.5 blocks/CU) there were only 4-6 waves/CU - the pipeline had
// nothing to overlap with (m102 regime: 320 TF @ grid 256). 8 waves/block
// doubles resident waves at identical grids; __launch_bounds__(512,4) caps
// VGPR at 128 so 2 blocks/CU co-reside where grid >= 512.
// Wave w: 64x32 quadrant (wm=w>>2, wn=w&3), 8 MFMA/K-step.
// Staging: 16 chunks (A 8, B 8; chunk = 16 rows x 32 cols = 1KB), wave w
// stages chunks 2w, 2w+1 (A rows w*32.. for w<4, B rows (w-4)*32.. else).
// LDS 2 x 16KB; buffer select by offset arithmetic (gfx950 addrspace-select
// miscompile if LDS pointers go through a ternary into global_load_lds).
// ---------------------------------------------------------------------------
template <int CF32>
__global__ __launch_bounds__(512, 4)
void gemm_bt(const u16* __restrict__ A, const u16* __restrict__ B,
             void* __restrict__ Cv, int K, int lda, int ldb, int ldc)
{
    const int tid = threadIdx.x;
    const int w = tid >> 6, lane = tid & 63;
    const int q = lane >> 4, r = lane & 15;
    const int tm = blockIdx.y, tn = blockIdx.x;

    __shared__ __align__(16) u16 smem[2 * 8192];   // buf b: A chunks [0,4096), B [4096,8192)

    const int lr = lane & 15;
    const int lc = (lane >> 4) * 8;
    const long ld = (w < 4) ? (long)lda : (long)ldb;
    const u16* g0 = ((w < 4)
        ? A + (long)(tm * 128 + w * 32 + lr) * lda
        : B + (long)(tn * 128 + (w - 4) * 32 + lr) * ldb) + lc;
    const u16* g1 = g0 + 16 * ld;
    const int s0 = w * 1024;
    const int s1 = s0 + 512;

    f32x4 acc[4][2] = {};
    const int wm = w >> 2;      // 0..1  (64-row half)
    const int wn = w & 3;       // 0..3  (32-col quarter)

    // prologue: stage k0=0 into buffer 0
    gl_lds16(g0, smem + s0);
    gl_lds16(g1, smem + s1);
    __syncthreads();

    int p = 0;
    for (int k0 = 0; k0 < K; k0 += 32) {
        u16* const cur = smem + p * 8192;
        u16* const nxt = smem + (p ^ 1) * 8192;
        if (k0 + 32 < K) {      // prefetch next K-step
            gl_lds16(g0 + k0 + 32, nxt + s0);
            gl_lds16(g1 + k0 + 32, nxt + s1);
        }
        bf16x8 af[4], bv[2];
        #pragma unroll
        for (int mt = 0; mt < 4; ++mt)
            af[mt] = *(const bf16x8*)&cur[(wm * 4 + mt) * 512 + lane * 8];
        #pragma unroll
        for (int nt = 0; nt < 2; ++nt)
            bv[nt] = *(const bf16x8*)&cur[4096 + (wn * 2 + nt) * 512 + lane * 8];
        #pragma unroll
        for (int mt = 0; mt < 4; ++mt)
            #pragma unroll
            for (int nt = 0; nt < 2; ++nt)
                acc[mt][nt] = __builtin_amdgcn_mfma_f32_16x16x32_bf16(
                    af[mt], bv[nt], acc[mt][nt], 0, 0, 0);
        __syncthreads();   // drains prefetch + buffer swap
        p ^= 1;
    }

    const int row0 = tm * 128 + wm * 64 + q * 4;
    const int col0 = tn * 128 + wn * 32 + r;
    if (CF32) {
        float* C = (float*)Cv;
        #pragma unroll
        for (int mt = 0; mt < 4; ++mt)
            #pragma unroll
            for (int i = 0; i < 4; ++i) {
                long rb = (long)(row0 + mt * 16 + i) * ldc + col0;
                #pragma unroll
                for (int nt = 0; nt < 2; ++nt)
                    C[rb + nt * 16] = acc[mt][nt][i];
            }
    } else {
        u16* C = (u16*)Cv;
        #pragma unroll
        for (int mt = 0; mt < 4; ++mt)
            #pragma unroll
            for (int i = 0; i < 4; ++i) {
                long rb = (long)(row0 + mt * 16 + i) * ldc + col0;
                #pragma unroll
                for (int nt = 0; nt < 2; ++nt)
                    C[rb + nt * 16] = f2bf(acc[mt][nt][i]);
            }
    }
}

// ---------------------------------------------------------------------------
// Flash attention, S^T formulation, double-buffered prefetch pipeline.
// (unchanged from round 5: 4-wave blocks, kv-tile 64, conflict-free PV b128
// via s-permuted vt, maxless exp2-domain softmax, complementary pairing.)
// ---------------------------------------------------------------------------
template<int C0, int C1>
__device__ __forceinline__ void stage_tile(
    const u16* __restrict__ kvb, const u16* __restrict__ kpe,
    const u16* __restrict__ vt,
    u16* __restrict__ Kl, u16* __restrict__ Vl,
    int h, int t, int quad, int r)
{
    #pragma unroll
    for (int c = C0; c < C1; ++c) {
        if (c < 24) {
            const int mtk = c / 6, kc = c % 6;
            const int row = t * 64 + mtk * 16 + r;
            const u16* src = (kc < 4)
                ? kvb + (size_t)row * 4096 + h * 256 + kc * 32 + quad * 8
                : kpe + (size_t)row * 64 + (kc - 4) * 32 + quad * 8;
            gl_lds16(src, &Kl[c * 512]);
        } else {
            const int cv = c - 24, mtd = cv >> 1, sc = cv & 1;
            const u16* src = vt + ((size_t)h * 128 + mtd * 16 + r) * 2048
                             + t * 64 + sc * 32 + quad * 8;
            gl_lds16(src, &Vl[cv * 512]);
        }
    }
}

__device__ __forceinline__ void stage_dispatch(
    const u16* __restrict__ kvb, const u16* __restrict__ kpe,
    const u16* __restrict__ vt,
    u16* __restrict__ Kl, u16* __restrict__ Vl,
    int w, int h, int t, int quad, int r)
{
    if (w == 0)      stage_tile<0, 10>(kvb, kpe, vt, Kl, Vl, h, t, quad, r);
    else if (w == 1) stage_tile<10, 20>(kvb, kpe, vt, Kl, Vl, h, t, quad, r);
    else if (w == 2) stage_tile<20, 30>(kvb, kpe, vt, Kl, Vl, h, t, quad, r);
    else             stage_tile<30, 40>(kvb, kpe, vt, Kl, Vl, h, t, quad, r);
}

__device__ __forceinline__ void kv_tile_step(
    const u16* __restrict__ Kl, const u16* __restrict__ Vl,
    const bf16x8 (&Qf)[6], f32x4 (&Oacc)[8], float& lsum,
    int lane, int quad, int r, int kglob0, int qg, bool maskT)
{
    f32x4 Sacc[4];
    #pragma unroll
    for (int mtk = 0; mtk < 4; ++mtk)
        Sacc[mtk] = (f32x4){0.f, 0.f, 0.f, 0.f};
    #pragma unroll
    for (int kc = 0; kc < 6; ++kc)
        #pragma unroll
        for (int mtk = 0; mtk < 4; ++mtk) {
            bf16x8 Ak = *(const bf16x8*)&Kl[(mtk * 6 + kc) * 512 + lane * 8];
            Sacc[mtk] = __builtin_amdgcn_mfma_f32_16x16x32_bf16(
                Ak, Qf[kc], Sacc[mtk], 0, 0, 0);
        }
    #pragma unroll
    for (int sc = 0; sc < 2; ++sc) {
        s16x4 Pf[2];
        #pragma unroll
        for (int half = 0; half < 2; ++half) {
            const int kb = sc * 2 + half;
            const int kb0 = kglob0 + kb * 16 + quad * 4;
            #pragma unroll
            for (int i = 0; i < 4; ++i) {
                float pv = exp2f(Sacc[kb][i]);
                if (maskT && (kb0 + i > qg)) pv = 0.f;
                lsum += pv;
                Pf[half][i] = (short)f2bf(pv);
            }
        }
        #pragma unroll
        for (int mtd = 0; mtd < 8; ++mtd) {
            s16x8 Av8 = *(const s16x8*)&Vl[(mtd * 2 + sc) * 512 + quad * 128 + r * 8];
            s16x4 lo = __builtin_shufflevector(Av8, Av8, 0, 1, 2, 3);
            s16x4 hi = __builtin_shufflevector(Av8, Av8, 4, 5, 6, 7);
            Oacc[mtd] = mfma16(lo, Pf[0], Oacc[mtd]);
            Oacc[mtd] = mfma16(hi, Pf[1], Oacc[mtd]);
        }
    }
}

__global__ __launch_bounds__(256, 2)
void flash_attn(const u16* __restrict__ query, const u16* __restrict__ kvb,
                const u16* __restrict__ kpe, const u16* __restrict__ vt,
                u16* __restrict__ ao)
{
    const int tid = threadIdx.x;
    const int w = tid >> 6, lane = tid & 63;
    const int quad = lane >> 4, r = lane & 15;

    // Complementary work pairing (blocks b and b+256 share a CU).
    const int bid = (int)blockIdx.x;
    const int i = bid & 255;
    const int t_ = i >> 4;
    const int h = i & 15;
    const int j = (bid < 256) ? (31 - t_) : t_;

    const int q0 = j * 64;
    const int ntk = j + 1;          // 64-wide kv tiles up to the diagonal

    __shared__ __align__(16) u16 smem[40960];   // 80KB: two 40KB tile buffers
    // buffer b at smem + b*20480: K = [0,12288) u16, V = [12288,20480) u16

    const int qg = q0 + w * 16 + r;   // this wave's q row (causal bound)

    bf16x8 Qf[6];
    #pragma unroll
    for (int kc = 0; kc < 6; ++kc)
        Qf[kc] = *(const bf16x8*)(query
            + ((size_t)h * S_LEN + q0 + w * 16 + r) * QHEAD
            + kc * 32 + quad * 8);

    f32x4 Oacc[8];
    #pragma unroll
    for (int mtd = 0; mtd < 8; ++mtd)
        Oacc[mtd] = (f32x4){0.f, 0.f, 0.f, 0.f};
    float lsum = 0.f;

    // prologue: stage tile 0 into buffer 0
    stage_dispatch(kvb, kpe, vt, smem, smem + 12288, w, h, 0, quad, r);
    __syncthreads();

    for (int t = 0; t < ntk; ++t) {
        u16* const curb = smem + (t & 1) * 20480;          // offset arith,
        u16* const nxtb = smem + ((t + 1) & 1) * 20480;    // no ptr select
        if (t + 1 < ntk)   // prefetch next tile into the other buffer
            stage_dispatch(kvb, kpe, vt, nxtb, nxtb + 12288, w, h, t + 1, quad, r);
        kv_tile_step(curb, curb + 12288, Qf, Oacc, lsum,
                     lane, quad, r, t * 64, qg, t == ntk - 1);
        __syncthreads();   // drains prefetch vmcnt + syncs buffer swap
    }

    // epilogue: each wave owns its 16 q-rows; reduce lsum over quads only
    float l = lsum;
    l += __shfl_xor(l, 16, 64);
    l += __shfl_xor(l, 32, 64);
    const float inv = 1.0f / l;
    const int qrow = q0 + w * 16 + r;
    #pragma unroll
    for (int mtd = 0; mtd < 8; ++mtd) {
        ushort4 o;
        o.x = f2bf(Oacc[mtd][0] * inv);
        o.y = f2bf(Oacc[mtd][1] * inv);
        o.z = f2bf(Oacc[mtd][2] * inv);
        o.w = f2bf(Oacc[mtd][3] * inv);
        *(ushort4*)(ao + (size_t)qrow * 2048 + h * 128 + mtd * 16 + quad * 4) = o;
    }
}

// ---------------------------------------------------------------------------
__global__ __launch_bounds__(256)
void cvt_f32_bf16(const float4* __restrict__ in, ushort4* __restrict__ out, int n4)
{
    int i = blockIdx.x * 256 + threadIdx.x;
    if (i < n4) {
        float4 v = in[i];
        ushort4 o;
        o.x = f2bf(v.x); o.y = f2bf(v.y); o.z = f2bf(v.z); o.w = f2bf(v.w);
        out[i] = o;
    }
}

// in fp32 [K][N] -> out bf16 [Npad][K], rows >= N zero-filled.
__global__ __launch_bounds__(256)
void wtrans_k(const float* __restrict__ in, u16* __restrict__ out, int K, int N)
{
    __shared__ float tile[32][33];
    int k0 = blockIdx.x * 32, n0 = blockIdx.y * 32;
    int tx = threadIdx.x, ty = threadIdx.y;
    #pragma unroll
    for (int j = 0; j < 32; j += 8) {
        int n = n0 + tx;
        tile[ty + j][tx] = (n < N) ? in[(long)(k0 + ty + j) * N + n] : 0.0f;
    }
    __syncthreads();
    #pragma unroll
    for (int j = 0; j < 32; j += 8)
        out[(long)(n0 + ty + j) * K + k0 + tx] = f2bf(tile[tx][ty + j]);
}

// RMS norm in-place on first D cols of rows with stride ld.
__global__ __launch_bounds__(256)
void rmsnorm_k(u16* __restrict__ X, const float* __restrict__ w, int D, int ld)
{
    u16* row = X + (long)blockIdx.x * ld;
    const int tid = threadIdx.x;
    __shared__ float red[4];
    float sum = 0.f;
    for (int d = tid; d < D; d += 256) { float v = bf2f(row[d]); sum += v * v; }
    #pragma unroll
    for (int o = 32; o; o >>= 1) sum += __shfl_xor(sum, o, 64);
    if ((tid & 63) == 0) red[tid >> 6] = sum;
    __syncthreads();
    sum = red[0] + red[1] + red[2] + red[3];
    float scale = rsqrtf(sum / (float)D + EPS);
    for (int d = tid; d < D; d += 256)
        row[d] = f2bf(bf2f(row[d]) * scale * w[d]);
}

// qkv_a bf16 [S][2176] cols 1536.. = [c(512)|k_pe(64)] -> kv_cache fp32
// [S][576], c_norm bf16 [S][512], roped k_pe bf16 [S][64].
__global__ __launch_bounds__(256)
void kvcache_k(const u16* __restrict__ qkv, const float* __restrict__ ln,
               const int* __restrict__ pos_ids, const float* __restrict__ cosb,
               const float* __restrict__ sinb, float* __restrict__ kvout,
               u16* __restrict__ cnb, u16* __restrict__ kpe)
{
    const int s = blockIdx.x, tid = threadIdx.x;
    const u16* row = qkv + (long)s * 2176 + 1536;
    __shared__ float red[4];
    float sum = 0.f;
    for (int d = tid; d < 512; d += 256) { float v = bf2f(row[d]); sum += v * v; }
    #pragma unroll
    for (int o = 32; o; o >>= 1) sum += __shfl_xor(sum, o, 64);
    if ((tid & 63) == 0) red[tid >> 6] = sum;
    __syncthreads();
    sum = red[0] + red[1] + red[2] + red[3];
    float scale = rsqrtf(sum / 512.f + EPS);
    for (int d = tid; d < 512; d += 256) {
        float v = bf2f(row[d]) * scale * ln[d];
        kvout[(long)s * 576 + d] = v;
        cnb[(long)s * 512 + d] = f2bf(v);
    }
    if (tid < 32) {
        int p = pos_ids[s];
        float x0 = bf2f(row[512 + 2 * tid]);
        float x1 = bf2f(row[512 + 2 * tid + 1]);
        float c1 = cosb[p * 64 + tid], s1 = sinb[p * 64 + tid];
        float c2 = cosb[p * 64 + 32 + tid], s2 = sinb[p * 64 + 32 + tid];
        float lo = x0 * c1 - x1 * s1;
        float hi = x1 * c2 + x0 * s2;
        kvout[(long)s * 576 + 512 + tid] = lo;
        kvout[(long)s * 576 + 544 + tid] = hi;
        kpe[(long)s * 64 + tid] = f2bf(lo);
        kpe[(long)s * 64 + 32 + tid] = f2bf(hi);
    }
}

// q bf16 [S][3072] -> query bf16 [H][S][192], rope on last 64 dims,
// all values pre-scaled by SCALE*log2(e) for exp2-domain softmax.
__global__ __launch_bounds__(256)
void qrope_k(const u16* __restrict__ qb, const int* __restrict__ pos_ids,
             const float* __restrict__ cosb, const float* __restrict__ sinb,
             u16* __restrict__ query)
{
    const int s = blockIdx.x, tid = threadIdx.x;
    const u16* row = qb + (long)s * 3072;
    {   // nope part: 16 heads x 16 chunks of 8, scaled
        int h = tid >> 4, c = tid & 15;
        const u16* src = &row[h * QHEAD + c * 8];
        u16* dst = &query[((long)(h * S_LEN + s)) * QHEAD + c * 8];
        ushort4 a = *(const ushort4*)src;
        ushort4 b = *(const ushort4*)(src + 4);
        ushort4 oa, ob;
        oa.x = f2bf(bf2f(a.x) * QSCALE_LOG2E); oa.y = f2bf(bf2f(a.y) * QSCALE_LOG2E);
        oa.z = f2bf(bf2f(a.z) * QSCALE_LOG2E); oa.w = f2bf(bf2f(a.w) * QSCALE_LOG2E);
        ob.x = f2bf(bf2f(b.x) * QSCALE_LOG2E); ob.y = f2bf(bf2f(b.y) * QSCALE_LOG2E);
        ob.z = f2bf(bf2f(b.z) * QSCALE_LOG2E); ob.w = f2bf(bf2f(b.w) * QSCALE_LOG2E);
        *(ushort4*)dst = oa;
        *(ushort4*)(dst + 4) = ob;
    }
    int p = pos_ids[s];
    for (int idx = tid; idx < 512; idx += 256) {
        int h = idx >> 5, i = idx & 31;
        float x0 = bf2f(row[h * QHEAD + 128 + 2 * i]);
        float x1 = bf2f(row[h * QHEAD + 128 + 2 * i + 1]);
        float c1 = cosb[p * 64 + i], s1 = sinb[p * 64 + i];
        float c2 = cosb[p * 64 + 32 + i], s2 = sinb[p * 64 + 32 + i];
        u16* qr = query + ((long)(h * S_LEN + s)) * QHEAD;
        qr[128 + i] = f2bf((x0 * c1 - x1 * s1) * QSCALE_LOG2E);
        qr[160 + i] = f2bf((x1 * c2 + x0 * s2) * QSCALE_LOG2E);
    }
}

// kv bf16 [S][4096] value part -> vt bf16 [H*128][S] (transposed).
// The s-axis is permuted within each 32-block so flash PV can read b128:
// new position quad*8 + half*4 + i  <-> old s = half*16 + quad*4 + i.
__global__ __launch_bounds__(256)
void vtrans_k(const u16* __restrict__ kv, u16* __restrict__ vt)
{
    __shared__ u16 tile[32][33];
    int s0 = blockIdx.x * 32, d0 = blockIdx.y * 32, h = blockIdx.z;
    int tx = threadIdx.x, ty = threadIdx.y;
    #pragma unroll
    for (int j = 0; j < 32; j += 8)
        tile[ty + j][tx] = kv[(long)(s0 + ty + j) * 4096 + h * 256 + 128 + d0 + tx];
    __syncthreads();
    const int txp = ((tx >> 2) & 3) * 8 + (tx >> 4) * 4 + (tx & 3);
    #pragma unroll
    for (int j = 0; j < 32; j += 8)
        vt[(long)(h * 128 + d0 + ty + j) * S_LEN + s0 + txp] = tile[tx][ty + j];
}

// ---------------------------------------------------------------------------
extern "C" void kernel_launch(void* const* d_in, const int* in_sizes, int n_in,
                              void* d_out, int out_size, void* d_ws, size_t ws_size,
                              hipStream_t stream)
{
    const float* x      = (const float*)d_in[0];
    const int*   posid  = (const int*)d_in[2];
    const float* cosb   = (const float*)d_in[3];
    const float* sinb   = (const float*)d_in[4];
    const float* q_a_w  = (const float*)d_in[5];
    const float* q_a_ln = (const float*)d_in[6];
    const float* q_b_w  = (const float*)d_in[7];
    const float* kv_a_w = (const float*)d_in[8];
    const float* kv_a_ln= (const float*)d_in[9];
    const float* kv_b_w = (const float*)d_in[10];
    const float* o_w    = (const float*)d_in[11];

    float* out    = (float*)d_out;
    float* kv_out = out + (size_t)2048 * 2048;

    char* ws = (char*)d_ws;
    size_t off = 0;
    auto alloc = [&](size_t bytes) { char* p = ws + off; off += (bytes + 255) & ~(size_t)255; return p; };
    u16* xb    = (u16*)alloc(2048ULL * 2048 * 2);
    u16* W1    = (u16*)alloc(2176ULL * 2048 * 2);   // [q_a^T ; kv_a^T(pad 640)]
    u16* qbwt  = (u16*)alloc(3072ULL * 1536 * 2);
    u16* kvbwt = (u16*)alloc(4096ULL * 512 * 2);
    u16* owt   = (u16*)alloc(2048ULL * 2048 * 2);
    u16* qkv_a = (u16*)alloc(2048ULL * 2176 * 2);   // [q_a(1536) | ckv(640)]
    u16* qbuf  = (u16*)alloc(2048ULL * 3072 * 2);
    u16* query = (u16*)alloc(16ULL * 2048 * 192 * 2);
    u16* cnb   = (u16*)alloc(2048ULL * 512 * 2);
    u16* kpe   = (u16*)alloc(2048ULL * 64 * 2);
    u16* kvbuf = (u16*)alloc(2048ULL * 4096 * 2);
    u16* vt    = (u16*)alloc(16ULL * 128 * 2048 * 2);
    u16* ao    = (u16*)alloc(2048ULL * 2048 * 2);
    (void)ws_size; (void)in_sizes; (void)n_in; (void)out_size;

    dim3 blk(256);
    dim3 gblk(512);
    dim3 tblk(32, 8);

    // 0) conversions / weight transposes
    cvt_f32_bf16<<<dim3(4096), blk, 0, stream>>>((const float4*)x, (ushort4*)xb, 2048 * 2048 / 4);
    wtrans_k<<<dim3(64, 48),  tblk, 0, stream>>>(q_a_w,  W1,                    2048, 1536);
    wtrans_k<<<dim3(64, 20),  tblk, 0, stream>>>(kv_a_w, W1 + 1536ULL * 2048,   2048, 576);
    wtrans_k<<<dim3(48, 96),  tblk, 0, stream>>>(q_b_w,  qbwt,  1536, 3072);
    wtrans_k<<<dim3(16, 128), tblk, 0, stream>>>(kv_b_w, kvbwt, 512,  4096);
    wtrans_k<<<dim3(64, 64),  tblk, 0, stream>>>(o_w,    owt,   2048, 2048);

    // 1) [q_a | ckv] = x @ [q_a_w | kv_a_w]  (merged, N=2176)
    gemm_bt<0><<<dim3(17, 16), gblk, 0, stream>>>(xb, W1, qkv_a, 2048, 2048, 2048, 2176);
    rmsnorm_k<<<dim3(2048), blk, 0, stream>>>(qkv_a, q_a_ln, 1536, 2176);
    kvcache_k<<<dim3(2048), blk, 0, stream>>>(qkv_a, kv_a_ln, posid, cosb, sinb, kv_out, cnb, kpe);

    // 2) q = q_a_norm @ q_b_w ; rope + relayout (+ exp2-domain pre-scale)
    gemm_bt<0><<<dim3(24, 16), gblk, 0, stream>>>(qkv_a, qbwt, qbuf, 1536, 2176, 1536, 3072);
    qrope_k<<<dim3(2048), blk, 0, stream>>>(qbuf, posid, cosb, sinb, query);

    // 3) kv = c_norm @ kv_b_w ; transpose value (s-permuted for PV b128)
    gemm_bt<0><<<dim3(32, 16), gblk, 0, stream>>>(cnb, kvbwt, kvbuf, 512, 512, 512, 4096);
    vtrans_k<<<dim3(64, 4, 16), tblk, 0, stream>>>(kvbuf, vt);

    // 4) fused flash attention (pipelined double-buffer) -> ao bf16 [S][H*128]
    flash_attn<<<dim3(512), dim3(256), 0, stream>>>(query, kvbuf, kpe, vt, ao);

    // 5) out = ao @ o_w (fp32)
    gemm_bt<1><<<dim3(16, 16), gblk, 0, stream>>>(ao, owt, out, 2048, 2048, 2048, 2048);
}

// Round 7
// 397.411 us; speedup vs baseline: 1.2526x; 1.0503x over previous
//
#include <hip/hip_runtime.h>

typedef unsigned short u16;
typedef __bf16 bf16x8 __attribute__((ext_vector_type(8)));
typedef short s16x4 __attribute__((ext_vector_type(4)));
typedef short s16x8 __attribute__((ext_vector_type(8)));
typedef float f32x4 __attribute__((ext_vector_type(4)));

#define S_LEN 2048
#define NHEAD 16
#define QHEAD 192
#define EPS 1e-6f
#define ATTN_SCALE 0.07216878364870323f   /* 192^-0.5 */
#define QSCALE_LOG2E 0.10412011228586118f /* ATTN_SCALE * log2(e) */

__device__ __forceinline__ u16 f2bf(float f) {
    unsigned u = __builtin_bit_cast(unsigned, f);
    u = (u + 0x7FFFu + ((u >> 16) & 1u)) >> 16;
    return (u16)u;
}
__device__ __forceinline__ float bf2f(u16 h) {
    unsigned u = ((unsigned)h) << 16;
    return __builtin_bit_cast(float, u);
}

__device__ __forceinline__ void gl_lds16(const u16* g, u16* l) {
    __builtin_amdgcn_global_load_lds(
        (const __attribute__((address_space(1))) unsigned int*)g,
        (__attribute__((address_space(3))) unsigned int*)l,
        16, 0, 0);
}

#if defined(__has_builtin) && __has_builtin(__builtin_amdgcn_mfma_f32_16x16x16bf16_1k)
__device__ __forceinline__ f32x4 mfma16(s16x4 a, s16x4 b, f32x4 c) {
    return __builtin_amdgcn_mfma_f32_16x16x16bf16_1k(a, b, c, 0, 0, 0);
}
#else
__device__ __forceinline__ f32x4 mfma16(s16x4 a, s16x4 b, f32x4 c) {
    asm volatile("v_mfma_f32_16x16x16_bf16 %0, %1, %2, %0"
                 : "+v"(c) : "v"(a), "v"(b));
    return c;
}
#endif

// ---------------------------------------------------------------------------
// bf16 GEMM core:  C[M][N] = A[M][K] @ Bt[N][K]^T
// 8-wave (512-thread) blocks, 128x128 tile, DEPTH-2 prefetch with TRIPLE
// buffer and COUNTED vmcnt (T4). Round-6 post-mortem: __syncthreads drains
// vmcnt(0) including the just-issued prefetch, so each of the K/32
// iterations pays ~full L3/HBM latency -> ~60us per GEMM regardless of
// occupancy (rounds 5 and 6 both neutral). Here: issue loads for t+2,
// compute t, then `s_waitcnt vmcnt(2)` (only waits loads for t+1, leaves
// t+2's two loads in flight) + raw s_barrier. sched_barrier(0) fences
// keep the compiler from hoisting next-iter ds_reads above the wait
// (rule #18). Each wave issues exactly 2 global_load_lds per staged iter,
// no other VMEM in the loop -> counting is exact. LDS 3 x 16KB = 48KB.
// ---------------------------------------------------------------------------
template <int CF32>
__device__ __forceinline__ void gemm_core(
    u16* __restrict__ smem,
    const u16* __restrict__ A, const u16* __restrict__ B, void* __restrict__ Cv,
    int K, int lda, int ldb, int ldc, int tm, int tn)
{
    const int tid = threadIdx.x;
    const int w = tid >> 6, lane = tid & 63;
    const int q = lane >> 4, r = lane & 15;

    const int lr = lane & 15;
    const int lc = (lane >> 4) * 8;
    const long ld = (w < 4) ? (long)lda : (long)ldb;
    const u16* g0 = ((w < 4)
        ? A + (long)(tm * 128 + w * 32 + lr) * lda
        : B + (long)(tn * 128 + (w - 4) * 32 + lr) * ldb) + lc;
    const u16* g1 = g0 + 16 * ld;
    const int s0 = w * 1024;
    const int s1 = s0 + 512;

    f32x4 acc[4][2] = {};
    const int wm = w >> 2;      // 0..1  (64-row half)
    const int wn = w & 3;       // 0..3  (32-col quarter)
    const int n = K >> 5;       // iterations (>= 16 for all our K)

    // prologue: stage iters 0 and 1 into buffers 0 and 1 (4 loads/wave)
    gl_lds16(g0, smem + s0);
    gl_lds16(g1, smem + s1);
    gl_lds16(g0 + 32, smem + 8192 + s0);
    gl_lds16(g1 + 32, smem + 8192 + s1);
    asm volatile("s_waitcnt vmcnt(2)" ::: "memory");   // iter-0 loads done
    __builtin_amdgcn_sched_barrier(0);
    __builtin_amdgcn_s_barrier();
    __builtin_amdgcn_sched_barrier(0);

    int bc = 0;   // t % 3
    for (int t = 0; t < n; ++t) {
        u16* const cur = smem + bc * 8192;
        if (t + 2 < n) {        // stage iter t+2 (buffer read at t-1, barrier-safe)
            int bn = bc + 2; if (bn >= 3) bn -= 3;
            u16* const nxt = smem + bn * 8192;
            const long k2 = (long)(t + 2) << 5;
            gl_lds16(g0 + k2, nxt + s0);
            gl_lds16(g1 + k2, nxt + s1);
        }
        bf16x8 af[4], bv[2];
        #pragma unroll
        for (int mt = 0; mt < 4; ++mt)
            af[mt] = *(const bf16x8*)&cur[(wm * 4 + mt) * 512 + lane * 8];
        #pragma unroll
        for (int nt = 0; nt < 2; ++nt)
            bv[nt] = *(const bf16x8*)&cur[4096 + (wn * 2 + nt) * 512 + lane * 8];
        #pragma unroll
        for (int mt = 0; mt < 4; ++mt)
            #pragma unroll
            for (int nt = 0; nt < 2; ++nt)
                acc[mt][nt] = __builtin_amdgcn_mfma_f32_16x16x32_bf16(
                    af[mt], bv[nt], acc[mt][nt], 0, 0, 0);
        if (t + 1 < n) {
            // wait until loads for t+1 landed; keep t+2's (if any) in flight
            if (t + 2 < n) asm volatile("s_waitcnt vmcnt(2)" ::: "memory");
            else           asm volatile("s_waitcnt vmcnt(0)" ::: "memory");
            __builtin_amdgcn_sched_barrier(0);
            __builtin_amdgcn_s_barrier();
            __builtin_amdgcn_sched_barrier(0);
        }
        if (++bc == 3) bc = 0;
    }

    const int row0 = tm * 128 + wm * 64 + q * 4;
    const int col0 = tn * 128 + wn * 32 + r;
    if (CF32) {
        float* C = (float*)Cv;
        #pragma unroll
        for (int mt = 0; mt < 4; ++mt)
            #pragma unroll
            for (int i = 0; i < 4; ++i) {
                long rb = (long)(row0 + mt * 16 + i) * ldc + col0;
                #pragma unroll
                for (int nt = 0; nt < 2; ++nt)
                    C[rb + nt * 16] = acc[mt][nt][i];
            }
    } else {
        u16* C = (u16*)Cv;
        #pragma unroll
        for (int mt = 0; mt < 4; ++mt)
            #pragma unroll
            for (int i = 0; i < 4; ++i) {
                long rb = (long)(row0 + mt * 16 + i) * ldc + col0;
                #pragma unroll
                for (int nt = 0; nt < 2; ++nt)
                    C[rb + nt * 16] = f2bf(acc[mt][nt][i]);
            }
    }
}

template <int CF32>
__global__ __launch_bounds__(512, 4)
void gemm_bt(const u16* __restrict__ A, const u16* __restrict__ B,
             void* __restrict__ Cv, int K, int lda, int ldb, int ldc)
{
    __shared__ __align__(16) u16 smem[3 * 8192];
    gemm_core<CF32>(smem, A, B, Cv, K, lda, ldb, ldc, blockIdx.y, blockIdx.x);
}

// Two independent GEMMs in ONE dispatch (z selects), so they overlap on the
// GPU instead of serializing at 1-1.5 blocks/CU each. Early-exit blocks
// return before any barrier (whole block uniform - no hang).
__global__ __launch_bounds__(512, 4)
void gemm_bt_dual(const u16* __restrict__ A0, const u16* __restrict__ B0,
                  void* __restrict__ C0, int K0, int lda0, int ldb0, int ldc0, int nx0,
                  const u16* __restrict__ A1, const u16* __restrict__ B1,
                  void* __restrict__ C1, int K1, int lda1, int ldb1, int ldc1, int nx1)
{
    __shared__ __align__(16) u16 smem[3 * 8192];
    if (blockIdx.z == 0) {
        if ((int)blockIdx.x >= nx0) return;
        gemm_core<0>(smem, A0, B0, C0, K0, lda0, ldb0, ldc0, blockIdx.y, blockIdx.x);
    } else {
        if ((int)blockIdx.x >= nx1) return;
        gemm_core<0>(smem, A1, B1, C1, K1, lda1, ldb1, ldc1, blockIdx.y, blockIdx.x);
    }
}

// ---------------------------------------------------------------------------
// Flash attention, S^T formulation, double-buffered prefetch pipeline.
// (unchanged from round 6: 4-wave blocks, kv-tile 64, conflict-free PV b128
// via s-permuted vt, maxless exp2-domain softmax, complementary pairing.)
// ---------------------------------------------------------------------------
template<int C0, int C1>
__device__ __forceinline__ void stage_tile(
    const u16* __restrict__ kvb, const u16* __restrict__ kpe,
    const u16* __restrict__ vt,
    u16* __restrict__ Kl, u16* __restrict__ Vl,
    int h, int t, int quad, int r)
{
    #pragma unroll
    for (int c = C0; c < C1; ++c) {
        if (c < 24) {
            const int mtk = c / 6, kc = c % 6;
            const int row = t * 64 + mtk * 16 + r;
            const u16* src = (kc < 4)
                ? kvb + (size_t)row * 4096 + h * 256 + kc * 32 + quad * 8
                : kpe + (size_t)row * 64 + (kc - 4) * 32 + quad * 8;
            gl_lds16(src, &Kl[c * 512]);
        } else {
            const int cv = c - 24, mtd = cv >> 1, sc = cv & 1;
            const u16* src = vt + ((size_t)h * 128 + mtd * 16 + r) * 2048
                             + t * 64 + sc * 32 + quad * 8;
            gl_lds16(src, &Vl[cv * 512]);
        }
    }
}

__device__ __forceinline__ void stage_dispatch(
    const u16* __restrict__ kvb, const u16* __restrict__ kpe,
    const u16* __restrict__ vt,
    u16* __restrict__ Kl, u16* __restrict__ Vl,
    int w, int h, int t, int quad, int r)
{
    if (w == 0)      stage_tile<0, 10>(kvb, kpe, vt, Kl, Vl, h, t, quad, r);
    else if (w == 1) stage_tile<10, 20>(kvb, kpe, vt, Kl, Vl, h, t, quad, r);
    else if (w == 2) stage_tile<20, 30>(kvb, kpe, vt, Kl, Vl, h, t, quad, r);
    else             stage_tile<30, 40>(kvb, kpe, vt, Kl, Vl, h, t, quad, r);
}

__device__ __forceinline__ void kv_tile_step(
    const u16* __restrict__ Kl, const u16* __restrict__ Vl,
    const bf16x8 (&Qf)[6], f32x4 (&Oacc)[8], float& lsum,
    int lane, int quad, int r, int kglob0, int qg, bool maskT)
{
    f32x4 Sacc[4];
    #pragma unroll
    for (int mtk = 0; mtk < 4; ++mtk)
        Sacc[mtk] = (f32x4){0.f, 0.f, 0.f, 0.f};
    #pragma unroll
    for (int kc = 0; kc < 6; ++kc)
        #pragma unroll
        for (int mtk = 0; mtk < 4; ++mtk) {
            bf16x8 Ak = *(const bf16x8*)&Kl[(mtk * 6 + kc) * 512 + lane * 8];
            Sacc[mtk] = __builtin_amdgcn_mfma_f32_16x16x32_bf16(
                Ak, Qf[kc], Sacc[mtk], 0, 0, 0);
        }
    #pragma unroll
    for (int sc = 0; sc < 2; ++sc) {
        s16x4 Pf[2];
        #pragma unroll
        for (int half = 0; half < 2; ++half) {
            const int kb = sc * 2 + half;
            const int kb0 = kglob0 + kb * 16 + quad * 4;
            #pragma unroll
            for (int i = 0; i < 4; ++i) {
                float pv = exp2f(Sacc[kb][i]);
                if (maskT && (kb0 + i > qg)) pv = 0.f;
                lsum += pv;
                Pf[half][i] = (short)f2bf(pv);
            }
        }
        #pragma unroll
        for (int mtd = 0; mtd < 8; ++mtd) {
            s16x8 Av8 = *(const s16x8*)&Vl[(mtd * 2 + sc) * 512 + quad * 128 + r * 8];
            s16x4 lo = __builtin_shufflevector(Av8, Av8, 0, 1, 2, 3);
            s16x4 hi = __builtin_shufflevector(Av8, Av8, 4, 5, 6, 7);
            Oacc[mtd] = mfma16(lo, Pf[0], Oacc[mtd]);
            Oacc[mtd] = mfma16(hi, Pf[1], Oacc[mtd]);
        }
    }
}

__global__ __launch_bounds__(256, 2)
void flash_attn(const u16* __restrict__ query, const u16* __restrict__ kvb,
                const u16* __restrict__ kpe, const u16* __restrict__ vt,
                u16* __restrict__ ao)
{
    const int tid = threadIdx.x;
    const int w = tid >> 6, lane = tid & 63;
    const int quad = lane >> 4, r = lane & 15;

    // Complementary work pairing (blocks b and b+256 share a CU).
    const int bid = (int)blockIdx.x;
    const int i = bid & 255;
    const int t_ = i >> 4;
    const int h = i & 15;
    const int j = (bid < 256) ? (31 - t_) : t_;

    const int q0 = j * 64;
    const int ntk = j + 1;          // 64-wide kv tiles up to the diagonal

    __shared__ __align__(16) u16 smem[40960];   // 80KB: two 40KB tile buffers
    // buffer b at smem + b*20480: K = [0,12288) u16, V = [12288,20480) u16

    const int qg = q0 + w * 16 + r;   // this wave's q row (causal bound)

    bf16x8 Qf[6];
    #pragma unroll
    for (int kc = 0; kc < 6; ++kc)
        Qf[kc] = *(const bf16x8*)(query
            + ((size_t)h * S_LEN + q0 + w * 16 + r) * QHEAD
            + kc * 32 + quad * 8);

    f32x4 Oacc[8];
    #pragma unroll
    for (int mtd = 0; mtd < 8; ++mtd)
        Oacc[mtd] = (f32x4){0.f, 0.f, 0.f, 0.f};
    float lsum = 0.f;

    // prologue: stage tile 0 into buffer 0
    stage_dispatch(kvb, kpe, vt, smem, smem + 12288, w, h, 0, quad, r);
    __syncthreads();

    for (int t = 0; t < ntk; ++t) {
        u16* const curb = smem + (t & 1) * 20480;          // offset arith,
        u16* const nxtb = smem + ((t + 1) & 1) * 20480;    // no ptr select
        if (t + 1 < ntk)   // prefetch next tile into the other buffer
            stage_dispatch(kvb, kpe, vt, nxtb, nxtb + 12288, w, h, t + 1, quad, r);
        kv_tile_step(curb, curb + 12288, Qf, Oacc, lsum,
                     lane, quad, r, t * 64, qg, t == ntk - 1);
        __syncthreads();   // drains prefetch vmcnt + syncs buffer swap
    }

    // epilogue: each wave owns its 16 q-rows; reduce lsum over quads only
    float l = lsum;
    l += __shfl_xor(l, 16, 64);
    l += __shfl_xor(l, 32, 64);
    const float inv = 1.0f / l;
    const int qrow = q0 + w * 16 + r;
    #pragma unroll
    for (int mtd = 0; mtd < 8; ++mtd) {
        ushort4 o;
        o.x = f2bf(Oacc[mtd][0] * inv);
        o.y = f2bf(Oacc[mtd][1] * inv);
        o.z = f2bf(Oacc[mtd][2] * inv);
        o.w = f2bf(Oacc[mtd][3] * inv);
        *(ushort4*)(ao + (size_t)qrow * 2048 + h * 128 + mtd * 16 + quad * 4) = o;
    }
}

// ---------------------------------------------------------------------------
__global__ __launch_bounds__(256)
void cvt_f32_bf16(const float4* __restrict__ in, ushort4* __restrict__ out, int n4)
{
    int i = blockIdx.x * 256 + threadIdx.x;
    if (i < n4) {
        float4 v = in[i];
        ushort4 o;
        o.x = f2bf(v.x); o.y = f2bf(v.y); o.z = f2bf(v.z); o.w = f2bf(v.w);
        out[i] = o;
    }
}

// in fp32 [K][N] -> out bf16 [Npad][K], rows >= N zero-filled.
__global__ __launch_bounds__(256)
void wtrans_k(const float* __restrict__ in, u16* __restrict__ out, int K, int N)
{
    __shared__ float tile[32][33];
    int k0 = blockIdx.x * 32, n0 = blockIdx.y * 32;
    int tx = threadIdx.x, ty = threadIdx.y;
    #pragma unroll
    for (int j = 0; j < 32; j += 8) {
        int n = n0 + tx;
        tile[ty + j][tx] = (n < N) ? in[(long)(k0 + ty + j) * N + n] : 0.0f;
    }
    __syncthreads();
    #pragma unroll
    for (int j = 0; j < 32; j += 8)
        out[(long)(n0 + ty + j) * K + k0 + tx] = f2bf(tile[tx][ty + j]);
}

// RMS norm in-place on first D cols of rows with stride ld.
__global__ __launch_bounds__(256)
void rmsnorm_k(u16* __restrict__ X, const float* __restrict__ w, int D, int ld)
{
    u16* row = X + (long)blockIdx.x * ld;
    const int tid = threadIdx.x;
    __shared__ float red[4];
    float sum = 0.f;
    for (int d = tid; d < D; d += 256) { float v = bf2f(row[d]); sum += v * v; }
    #pragma unroll
    for (int o = 32; o; o >>= 1) sum += __shfl_xor(sum, o, 64);
    if ((tid & 63) == 0) red[tid >> 6] = sum;
    __syncthreads();
    sum = red[0] + red[1] + red[2] + red[3];
    float scale = rsqrtf(sum / (float)D + EPS);
    for (int d = tid; d < D; d += 256)
        row[d] = f2bf(bf2f(row[d]) * scale * w[d]);
}

// qkv_a bf16 [S][2176] cols 1536.. = [c(512)|k_pe(64)] -> kv_cache fp32
// [S][576], c_norm bf16 [S][512], roped k_pe bf16 [S][64].
__global__ __launch_bounds__(256)
void kvcache_k(const u16* __restrict__ qkv, const float* __restrict__ ln,
               const int* __restrict__ pos_ids, const float* __restrict__ cosb,
               const float* __restrict__ sinb, float* __restrict__ kvout,
               u16* __restrict__ cnb, u16* __restrict__ kpe)
{
    const int s = blockIdx.x, tid = threadIdx.x;
    const u16* row = qkv + (long)s * 2176 + 1536;
    __shared__ float red[4];
    float sum = 0.f;
    for (int d = tid; d < 512; d += 256) { float v = bf2f(row[d]); sum += v * v; }
    #pragma unroll
    for (int o = 32; o; o >>= 1) sum += __shfl_xor(sum, o, 64);
    if ((tid & 63) == 0) red[tid >> 6] = sum;
    __syncthreads();
    sum = red[0] + red[1] + red[2] + red[3];
    float scale = rsqrtf(sum / 512.f + EPS);
    for (int d = tid; d < 512; d += 256) {
        float v = bf2f(row[d]) * scale * ln[d];
        kvout[(long)s * 576 + d] = v;
        cnb[(long)s * 512 + d] = f2bf(v);
    }
    if (tid < 32) {
        int p = pos_ids[s];
        float x0 = bf2f(row[512 + 2 * tid]);
        float x1 = bf2f(row[512 + 2 * tid + 1]);
        float c1 = cosb[p * 64 + tid], s1 = sinb[p * 64 + tid];
        float c2 = cosb[p * 64 + 32 + tid], s2 = sinb[p * 64 + 32 + tid];
        float lo = x0 * c1 - x1 * s1;
        float hi = x1 * c2 + x0 * s2;
        kvout[(long)s * 576 + 512 + tid] = lo;
        kvout[(long)s * 576 + 544 + tid] = hi;
        kpe[(long)s * 64 + tid] = f2bf(lo);
        kpe[(long)s * 64 + 32 + tid] = f2bf(hi);
    }
}

// q bf16 [S][3072] -> query bf16 [H][S][192], rope on last 64 dims,
// all values pre-scaled by SCALE*log2(e) for exp2-domain softmax.
__global__ __launch_bounds__(256)
void qrope_k(const u16* __restrict__ qb, const int* __restrict__ pos_ids,
             const float* __restrict__ cosb, const float* __restrict__ sinb,
             u16* __restrict__ query)
{
    const int s = blockIdx.x, tid = threadIdx.x;
    const u16* row = qb + (long)s * 3072;
    {   // nope part: 16 heads x 16 chunks of 8, scaled
        int h = tid >> 4, c = tid & 15;
        const u16* src = &row[h * QHEAD + c * 8];
        u16* dst = &query[((long)(h * S_LEN + s)) * QHEAD + c * 8];
        ushort4 a = *(const ushort4*)src;
        ushort4 b = *(const ushort4*)(src + 4);
        ushort4 oa, ob;
        oa.x = f2bf(bf2f(a.x) * QSCALE_LOG2E); oa.y = f2bf(bf2f(a.y) * QSCALE_LOG2E);
        oa.z = f2bf(bf2f(a.z) * QSCALE_LOG2E); oa.w = f2bf(bf2f(a.w) * QSCALE_LOG2E);
        ob.x = f2bf(bf2f(b.x) * QSCALE_LOG2E); ob.y = f2bf(bf2f(b.y) * QSCALE_LOG2E);
        ob.z = f2bf(bf2f(b.z) * QSCALE_LOG2E); ob.w = f2bf(bf2f(b.w) * QSCALE_LOG2E);
        *(ushort4*)dst = oa;
        *(ushort4*)(dst + 4) = ob;
    }
    int p = pos_ids[s];
    for (int idx = tid; idx < 512; idx += 256) {
        int h = idx >> 5, i = idx & 31;
        float x0 = bf2f(row[h * QHEAD + 128 + 2 * i]);
        float x1 = bf2f(row[h * QHEAD + 128 + 2 * i + 1]);
        float c1 = cosb[p * 64 + i], s1 = sinb[p * 64 + i];
        float c2 = cosb[p * 64 + 32 + i], s2 = sinb[p * 64 + 32 + i];
        u16* qr = query + ((long)(h * S_LEN + s)) * QHEAD;
        qr[128 + i] = f2bf((x0 * c1 - x1 * s1) * QSCALE_LOG2E);
        qr[160 + i] = f2bf((x1 * c2 + x0 * s2) * QSCALE_LOG2E);
    }
}

// kv bf16 [S][4096] value part -> vt bf16 [H*128][S] (transposed).
// The s-axis is permuted within each 32-block so flash PV can read b128:
// new position quad*8 + half*4 + i  <-> old s = half*16 + quad*4 + i.
__global__ __launch_bounds__(256)
void vtrans_k(const u16* __restrict__ kv, u16* __restrict__ vt)
{
    __shared__ u16 tile[32][33];
    int s0 = blockIdx.x * 32, d0 = blockIdx.y * 32, h = blockIdx.z;
    int tx = threadIdx.x, ty = threadIdx.y;
    #pragma unroll
    for (int j = 0; j < 32; j += 8)
        tile[ty + j][tx] = kv[(long)(s0 + ty + j) * 4096 + h * 256 + 128 + d0 + tx];
    __syncthreads();
    const int txp = ((tx >> 2) & 3) * 8 + (tx >> 4) * 4 + (tx & 3);
    #pragma unroll
    for (int j = 0; j < 32; j += 8)
        vt[(long)(h * 128 + d0 + ty + j) * S_LEN + s0 + txp] = tile[tx][ty + j];
}

// ---------------------------------------------------------------------------
extern "C" void kernel_launch(void* const* d_in, const int* in_sizes, int n_in,
                              void* d_out, int out_size, void* d_ws, size_t ws_size,
                              hipStream_t stream)
{
    const float* x      = (const float*)d_in[0];
    const int*   posid  = (const int*)d_in[2];
    const float* cosb   = (const float*)d_in[3];
    const float* sinb   = (const float*)d_in[4];
    const float* q_a_w  = (const float*)d_in[5];
    const float* q_a_ln = (const float*)d_in[6];
    const float* q_b_w  = (const float*)d_in[7];
    const float* kv_a_w = (const float*)d_in[8];
    const float* kv_a_ln= (const float*)d_in[9];
    const float* kv_b_w = (const float*)d_in[10];
    const float* o_w    = (const float*)d_in[11];

    float* out    = (float*)d_out;
    float* kv_out = out + (size_t)2048 * 2048;

    char* ws = (char*)d_ws;
    size_t off = 0;
    auto alloc = [&](size_t bytes) { char* p = ws + off; off += (bytes + 255) & ~(size_t)255; return p; };
    u16* xb    = (u16*)alloc(2048ULL * 2048 * 2);
    u16* W1    = (u16*)alloc(2176ULL * 2048 * 2);   // [q_a^T ; kv_a^T(pad 640)]
    u16* qbwt  = (u16*)alloc(3072ULL * 1536 * 2);
    u16* kvbwt = (u16*)alloc(4096ULL * 512 * 2);
    u16* owt   = (u16*)alloc(2048ULL * 2048 * 2);
    u16* qkv_a = (u16*)alloc(2048ULL * 2176 * 2);   // [q_a(1536) | ckv(640)]
    u16* qbuf  = (u16*)alloc(2048ULL * 3072 * 2);
    u16* query = (u16*)alloc(16ULL * 2048 * 192 * 2);
    u16* cnb   = (u16*)alloc(2048ULL * 512 * 2);
    u16* kpe   = (u16*)alloc(2048ULL * 64 * 2);
    u16* kvbuf = (u16*)alloc(2048ULL * 4096 * 2);
    u16* vt    = (u16*)alloc(16ULL * 128 * 2048 * 2);
    u16* ao    = (u16*)alloc(2048ULL * 2048 * 2);
    (void)ws_size; (void)in_sizes; (void)n_in; (void)out_size;

    dim3 blk(256);
    dim3 gblk(512);
    dim3 tblk(32, 8);

    // 0) conversions / weight transposes
    cvt_f32_bf16<<<dim3(4096), blk, 0, stream>>>((const float4*)x, (ushort4*)xb, 2048 * 2048 / 4);
    wtrans_k<<<dim3(64, 48),  tblk, 0, stream>>>(q_a_w,  W1,                    2048, 1536);
    wtrans_k<<<dim3(64, 20),  tblk, 0, stream>>>(kv_a_w, W1 + 1536ULL * 2048,   2048, 576);
    wtrans_k<<<dim3(48, 96),  tblk, 0, stream>>>(q_b_w,  qbwt,  1536, 3072);
    wtrans_k<<<dim3(16, 128), tblk, 0, stream>>>(kv_b_w, kvbwt, 512,  4096);
    wtrans_k<<<dim3(64, 64),  tblk, 0, stream>>>(o_w,    owt,   2048, 2048);

    // 1) [q_a | ckv] = x @ [q_a_w | kv_a_w]  (merged, N=2176)
    gemm_bt<0><<<dim3(17, 16), gblk, 0, stream>>>(xb, W1, qkv_a, 2048, 2048, 2048, 2176);
    rmsnorm_k<<<dim3(2048), blk, 0, stream>>>(qkv_a, q_a_ln, 1536, 2176);
    kvcache_k<<<dim3(2048), blk, 0, stream>>>(qkv_a, kv_a_ln, posid, cosb, sinb, kv_out, cnb, kpe);

    // 2+3) q = q_a_norm @ q_b_w  AND  kv = c_norm @ kv_b_w  (one dispatch)
    gemm_bt_dual<<<dim3(32, 16, 2), gblk, 0, stream>>>(
        qkv_a, qbwt, qbuf, 1536, 2176, 1536, 3072, 24,
        cnb, kvbwt, kvbuf, 512, 512, 512, 4096, 32);
    qrope_k<<<dim3(2048), blk, 0, stream>>>(qbuf, posid, cosb, sinb, query);
    vtrans_k<<<dim3(64, 4, 16), tblk, 0, stream>>>(kvbuf, vt);

    // 4) fused flash attention (pipelined double-buffer) -> ao bf16 [S][H*128]
    flash_attn<<<dim3(512), dim3(256), 0, stream>>>(query, kvbuf, kpe, vt, ao);

    // 5) out = ao @ o_w (fp32)
    gemm_bt<1><<<dim3(16, 16), gblk, 0, stream>>>(ao, owt, out, 2048, 2048, 2048, 2048);
}